// Round 7
// baseline (194.815 us; speedup 1.0000x reference)
//
#include <hip/hip_runtime.h>

// Problem constants (from reference)
static constexpr int kB = 2, kS = 2048, kD = 1024, kFF = 4096;
static constexpr int kM = kB * kS;  // 4096 token rows
static constexpr size_t MB = 1u << 20;

typedef __attribute__((ext_vector_type(8))) short short8;
typedef __attribute__((ext_vector_type(4))) float f32x4;

__device__ __forceinline__ unsigned short f2bf(float f) {
  union { float f; unsigned int u; } c; c.f = f;
  unsigned int u = c.u;
  unsigned int r = u + 0x7FFFu + ((u >> 16) & 1u);  // RNE
  return (unsigned short)(r >> 16);
}

__device__ __forceinline__ float bf2f(unsigned short b) {
  union { unsigned int u; float f; } c;
  c.u = ((unsigned int)b) << 16;
  return c.f;
}

__device__ __forceinline__ void gload_lds16(const void* g, void* l) {
  __builtin_amdgcn_global_load_lds(
      (const __attribute__((address_space(1))) void*)g,
      (__attribute__((address_space(3))) void*)l, 16, 0, 0);
}

// ---------------- cast fp32 -> bf16 (vectorized) ----------------
__global__ __launch_bounds__(256) void cast_bf16_kernel(
    const float* __restrict__ in, unsigned short* __restrict__ out, int n) {
  int i = (blockIdx.x * 256 + threadIdx.x) * 4;
  if (i >= n) return;
  float4 v = *(const float4*)(in + i);
  ushort4 o;
  o.x = f2bf(v.x); o.y = f2bf(v.y); o.z = f2bf(v.z); o.w = f2bf(v.w);
  *(ushort4*)(out + i) = o;
}

// ------------- cast + transpose: W[K][N] fp32 -> Wt[N][K] bf16 (× scale) -------------
__global__ __launch_bounds__(1024) void cast_transpose_kernel(
    const float* __restrict__ W, unsigned short* __restrict__ Wt,
    int K, int N, float scale) {
  __shared__ float tile[32][33];
  int nb = blockIdx.x * 32, kb = blockIdx.y * 32;
  int tx = threadIdx.x, ty = threadIdx.y;
  tile[ty][tx] = W[(size_t)(kb + ty) * N + (nb + tx)];
  __syncthreads();
  Wt[(size_t)(nb + ty) * K + (kb + tx)] = f2bf(tile[tx][ty] * scale);
}

// --------- parallel GEMV phase 1: partial[b][n] = sum_{f in block b} bv[f]*Wo[f][n] ---
__global__ __launch_bounds__(256) void bias_gemv_part_kernel(
    const float* __restrict__ bv, const float* __restrict__ Wo,
    float* __restrict__ partial) {
  const int b = blockIdx.x, t = threadIdx.x;
  const int c = t * 4;
  float4 acc = {0.f, 0.f, 0.f, 0.f};
#pragma unroll
  for (int r = 0; r < 8; ++r) {
    const int f = b * 8 + r;
    const float s = bv[f];
    float4 w = *(const float4*)(Wo + (size_t)f * 1024 + c);
    acc.x = fmaf(s, w.x, acc.x);
    acc.y = fmaf(s, w.y, acc.y);
    acc.z = fmaf(s, w.z, acc.z);
    acc.w = fmaf(s, w.w, acc.w);
  }
  *(float4*)(partial + (size_t)b * 1024 + c) = acc;
}

// --------- GEMV phase 2: bc[n] = 2048 * sum_b partial[b][n] + bo[n] ---------
__global__ __launch_bounds__(256) void bias_gemv_fin_kernel(
    const float* __restrict__ partial, const float* __restrict__ bo,
    float* __restrict__ bc) {
  const int n = blockIdx.x * 256 + threadIdx.x;
  float acc = 0.0f;
#pragma unroll 8
  for (int b = 0; b < 128; ++b) acc += partial[(size_t)b * 1024 + n];
  bc[n] = 2048.0f * acc + bo[n];
}

// -------- combine 4 fp32 split-K partials of Wc, add identity, cast bf16 --------
__global__ __launch_bounds__(256) void combine_wc_kernel(
    const float* __restrict__ P, unsigned short* __restrict__ Wt) {
  const int i = (blockIdx.x * 256 + threadIdx.x) * 4;  // grid 1024
  const int MN = 1024 * 1024;
  float4 s0 = *(const float4*)(P + i);
  float4 s1 = *(const float4*)(P + MN + i);
  float4 s2 = *(const float4*)(P + 2 * MN + i);
  float4 s3 = *(const float4*)(P + 3 * MN + i);
  const int row = i >> 10, col = i & 1023;
  float v0 = s0.x + s1.x + s2.x + s3.x + (row == col + 0 ? 1.0f : 0.0f);
  float v1 = s0.y + s1.y + s2.y + s3.y + (row == col + 1 ? 1.0f : 0.0f);
  float v2 = s0.z + s1.z + s2.z + s3.z + (row == col + 2 ? 1.0f : 0.0f);
  float v3 = s0.w + s1.w + s2.w + s3.w + (row == col + 3 ? 1.0f : 0.0f);
  ushort4 o; o.x = f2bf(v0); o.y = f2bf(v1); o.z = f2bf(v2); o.w = f2bf(v3);
  *(ushort4*)(Wt + i) = o;
}

// ---------------- GEMM: C[M,N] = A[M,K] @ Bt[N,K]^T (+bias, opt relu, split-K) ----
// 128x128 tile, BK=64, 4 waves (2x2). Single 32KB LDS buffer (m97 structure:
// stage -> sync -> 16 MFMA -> sync, relies on multi-block TLP for overlap).
// T2 XOR-swizzle (both-sides, rule 21): conflict-free (measured 0 in r4/r5/r6).
// T1 bijective XCD swizzle.
template <int OUT_BF16, int RELU>
__global__ __launch_bounds__(256, 4) void gemm_bt(
    const unsigned short* __restrict__ A, const unsigned short* __restrict__ Bt,
    const float* __restrict__ bias, void* __restrict__ Cout,
    int M, int N, int K, int nXtiles, int nTilesPerSplit, int kSplitLen,
    size_t cSplitStride) {
  __shared__ __align__(16) unsigned short sA[128 * 64];
  __shared__ __align__(16) unsigned short sB[128 * 64];
  const int tid = threadIdx.x;
  const int wave = tid >> 6, lane = tid & 63;
  const int wr = wave >> 1, wc = wave & 1;
  const int nwg = gridDim.x;
  const int q = nwg >> 3, r = nwg & 7;
  const int xcd = blockIdx.x & 7, pos = blockIdx.x >> 3;
  const int swz = (xcd < r) ? (xcd * (q + 1) + pos) : (r * (q + 1) + (xcd - r) * q + pos);
  const int split = swz / nTilesPerSplit, rem = swz % nTilesPerSplit;
  const int m0 = (rem / nXtiles) * 128, n0 = (rem % nXtiles) * 128;
  const int kBeg = split * kSplitLen, kEnd = kBeg + kSplitLen;
  const int srow = lane >> 3;
  const int scol = ((lane & 7) ^ srow) * 8;  // pre-swizzled global col (elements)

  f32x4 acc[4][4] = {};

  for (int k0 = kBeg; k0 < kEnd; k0 += 64) {
#pragma unroll
    for (int i = 0; i < 4; ++i) {
      const int chunk = i * 4 + wave;
      const int rr = chunk * 8 + srow;
      gload_lds16(A + (size_t)(m0 + rr) * K + (k0 + scol), &sA[chunk * 512]);
      gload_lds16(Bt + (size_t)(n0 + rr) * K + (k0 + scol), &sB[chunk * 512]);
    }
    __syncthreads();
#pragma unroll
    for (int kk = 0; kk < 64; kk += 32) {
      const int kcol = kk + (lane >> 4) * 8;
      const int kswz = (lane & 7) * 8;
      short8 af[4], bfr[4];
#pragma unroll
      for (int m = 0; m < 4; ++m)
        af[m] = *(const short8*)&sA[(wr * 64 + m * 16 + (lane & 15)) * 64 + (kcol ^ kswz)];
#pragma unroll
      for (int n = 0; n < 4; ++n)
        bfr[n] = *(const short8*)&sB[(wc * 64 + n * 16 + (lane & 15)) * 64 + (kcol ^ kswz)];
#pragma unroll
      for (int m = 0; m < 4; ++m)
#pragma unroll
        for (int n = 0; n < 4; ++n)
          acc[m][n] = __builtin_amdgcn_mfma_f32_16x16x32_bf16(af[m], bfr[n], acc[m][n], 0, 0, 0);
    }
    __syncthreads();
  }

  const int cl = lane & 15, rg = lane >> 4;
  const float* bptr = (split == 0) ? bias : nullptr;
#pragma unroll
  for (int n = 0; n < 4; ++n) {
    const int col = n0 + wc * 64 + n * 16 + cl;
    const float bias_v = bptr ? bptr[col] : 0.0f;
#pragma unroll
    for (int m = 0; m < 4; ++m) {
      const int rbase = m0 + wr * 64 + m * 16 + rg * 4;
#pragma unroll
      for (int j = 0; j < 4; ++j) {
        float v = acc[m][n][j] + bias_v;
        if (RELU) v = fmaxf(v, 0.0f);
        if (OUT_BF16)
          ((unsigned short*)Cout)[(size_t)(rbase + j) * N + col] = f2bf(v);
        else
          ((float*)Cout)[split * cSplitStride + (size_t)(rbase + j) * N + col] = v;
      }
    }
  }
}

// -------- LN over D=1024 of one fp32 input -> bf16 out --------
__global__ __launch_bounds__(256) void ln1_bf16_kernel(
    const float* __restrict__ X,
    const float* __restrict__ gg, const float* __restrict__ bb,
    unsigned short* __restrict__ Hb) {
  const int row = blockIdx.x, t = threadIdx.x;
  const size_t base = (size_t)row * 1024 + t * 4;
  float4 xv = *(const float4*)(X + base);
  float a0 = xv.x, a1 = xv.y, a2 = xv.z, a3 = xv.w;
  float s = a0 + a1 + a2 + a3;
  float ss = a0 * a0 + a1 * a1 + a2 * a2 + a3 * a3;
#pragma unroll
  for (int off = 32; off > 0; off >>= 1) {
    s += __shfl_down(s, off);
    ss += __shfl_down(ss, off);
  }
  __shared__ float rs[4], rss[4];
  __shared__ float smean, srstd;
  const int wave = t >> 6, lane = t & 63;
  if (lane == 0) { rs[wave] = s; rss[wave] = ss; }
  __syncthreads();
  if (t == 0) {
    float S1 = rs[0] + rs[1] + rs[2] + rs[3];
    float S2 = rss[0] + rss[1] + rss[2] + rss[3];
    float mean = S1 * (1.0f / 1024.0f);
    float var = S2 * (1.0f / 1024.0f) - mean * mean;
    smean = mean;
    srstd = rsqrtf(var + 1e-5f);
  }
  __syncthreads();
  const float mean = smean, rstd = srstd;
  float4 gv = *(const float4*)(gg + t * 4);
  float4 bv = *(const float4*)(bb + t * 4);
  ushort4 hb;
  hb.x = f2bf((a0 - mean) * rstd * gv.x + bv.x);
  hb.y = f2bf((a1 - mean) * rstd * gv.y + bv.y);
  hb.z = f2bf((a2 - mean) * rstd * gv.z + bv.z);
  hb.w = f2bf((a3 - mean) * rstd * gv.w + bv.w);
  *(ushort4*)(Hb + base) = hb;
}

// -------- LN of (bf16 residual + fp32 input) -> fp32 out --------
__global__ __launch_bounds__(256) void ln_fin_kernel(
    const unsigned short* __restrict__ Res, const float* __restrict__ P,
    const float* __restrict__ gg, const float* __restrict__ bb,
    float* __restrict__ out) {
  const int row = blockIdx.x, t = threadIdx.x;
  const size_t base = (size_t)row * 1024 + t * 4;
  ushort4 rv = *(const ushort4*)(Res + base);
  float4 v0 = *(const float4*)(P + base);
  float a0 = bf2f(rv.x) + v0.x;
  float a1 = bf2f(rv.y) + v0.y;
  float a2 = bf2f(rv.z) + v0.z;
  float a3 = bf2f(rv.w) + v0.w;
  float s = a0 + a1 + a2 + a3;
  float ss = a0 * a0 + a1 * a1 + a2 * a2 + a3 * a3;
#pragma unroll
  for (int off = 32; off > 0; off >>= 1) {
    s += __shfl_down(s, off);
    ss += __shfl_down(ss, off);
  }
  __shared__ float rs[4], rss[4];
  __shared__ float smean, srstd;
  const int wave = t >> 6, lane = t & 63;
  if (lane == 0) { rs[wave] = s; rss[wave] = ss; }
  __syncthreads();
  if (t == 0) {
    float S1 = rs[0] + rs[1] + rs[2] + rs[3];
    float S2 = rss[0] + rss[1] + rss[2] + rss[3];
    float mean = S1 * (1.0f / 1024.0f);
    float var = S2 * (1.0f / 1024.0f) - mean * mean;
    smean = mean;
    srstd = rsqrtf(var + 1e-5f);
  }
  __syncthreads();
  const float mean = smean, rstd = srstd;
  float4 gv = *(const float4*)(gg + t * 4);
  float4 bv = *(const float4*)(bb + t * 4);
  float4 ov;
  ov.x = (a0 - mean) * rstd * gv.x + bv.x;
  ov.y = (a1 - mean) * rstd * gv.y + bv.y;
  ov.z = (a2 - mean) * rstd * gv.z + bv.z;
  ov.w = (a3 - mean) * rstd * gv.w + bv.w;
  *(float4*)(out + base) = ov;
}

// ---------------------------------------------------------------------------
// Attention is algebraically dead: softmax over q sums to 1 per (b,h,k) column;
// summed over k -> s_bh == S == 2048 exactly. Folding the residual too:
//   h1  = LN( z @ (I + 2048*Wv@Wo) + (2048*bv@Wo + bo) )
//   out = LN( h1 + relu(h1@W1+b1)@W2 + b2 )
// q, k, mask, x, y, Wq, Wk are all unused.
// ---------------------------------------------------------------------------
extern "C" void kernel_launch(void* const* d_in, const int* in_sizes, int n_in,
                              void* d_out, int out_size, void* d_ws, size_t ws_size,
                              hipStream_t stream) {
  const float* z  = (const float*)d_in[2];
  const float* Wv = (const float*)d_in[8];
  const float* bv = (const float*)d_in[9];
  const float* Wo = (const float*)d_in[10];
  const float* bo = (const float*)d_in[11];
  const float* W1 = (const float*)d_in[12];
  const float* b1 = (const float*)d_in[13];
  const float* W2 = (const float*)d_in[14];
  const float* b2 = (const float*)d_in[15];
  const float* lng = (const float*)d_in[16];
  const float* lnb = (const float*)d_in[17];
  float* out = (float*)d_out;

  char* ws = (char*)d_ws;
  // layout (MB offsets), peak 96MB:
  //   zbf  @0-8    (dead after att GEMM) / a1 @0-32 (written at FF1)
  //   wcp  @32-48  (4 fp32 Wc partials; dead after combine)
  //   att  @48-64  (fp32; dead after LN1)
  //   ff   @64-80  (fp32)
  //   wT   @80-88  (W1T then W2T)
  //   WoT @88-90, WvBf @90-92, WcT @92-94, bc @94, bprt @94+64KB
  //   h1bf @95-...: need 8MB -> put at 88? conflicts with WoT.
  //   -> h1bf @ 48+... reuse att? att dead after LN1 but h1bf written BY LN1.
  //   Safe: h1bf @ 32-40 (over wcp, dead after combine which precedes LN1).
  unsigned short* zbf  = (unsigned short*)(ws + 0 * MB);
  unsigned short* a1   = (unsigned short*)(ws + 0 * MB);
  float*          wcp  = (float*)(ws + 32 * MB);
  unsigned short* h1bf = (unsigned short*)(ws + 32 * MB);  // after wcp dead
  float*          att  = (float*)(ws + 48 * MB);
  float*          ff   = (float*)(ws + 64 * MB);
  unsigned short* wT   = (unsigned short*)(ws + 80 * MB);
  unsigned short* WoT  = (unsigned short*)(ws + 88 * MB);
  unsigned short* WvBf = (unsigned short*)(ws + 90 * MB);
  unsigned short* WcT  = (unsigned short*)(ws + 92 * MB);
  float*          bc   = (float*)(ws + 94 * MB);
  float*          bprt = (float*)(ws + 94 * MB + 65536);

  const int nZ = kM * kD;  // 4194304

  // --- weight prep ---
  cast_transpose_kernel<<<dim3(kD / 32, kD / 32), dim3(32, 32), 0, stream>>>(
      Wo, WoT, kD, kD, (float)kS);                 // WoT[n][f] = 2048*Wo[f][n]
  cast_bf16_kernel<<<dim3(kD * kD / 1024), dim3(256), 0, stream>>>(Wv, WvBf, kD * kD);
  bias_gemv_part_kernel<<<dim3(128), dim3(256), 0, stream>>>(bv, Wo, bprt);
  bias_gemv_fin_kernel<<<dim3(4), dim3(256), 0, stream>>>(bprt, bo, bc);
  cast_bf16_kernel<<<dim3(nZ / 1024), dim3(256), 0, stream>>>(z, zbf, nZ);

  // WcT = (2048*Wv@Wo)^T via 128-tile split-K x4 (wcp @32MB), combine + I + bf16
  gemm_bt<0, 0><<<dim3(256), dim3(256), 0, stream>>>(
      WoT, WvBf, nullptr, wcp, kD, kD, kD, kD / 128, 64, 256, (size_t)kD * kD);
  combine_wc_kernel<<<dim3(1024), dim3(256), 0, stream>>>(wcp, WcT);

  // att = z @ (I+Wc) + bc : grid 256 (32x8 tiles), K=1024 (16 steps), no split
  gemm_bt<0, 0><<<dim3(256), dim3(256), 0, stream>>>(
      zbf, WcT, bc, att, kM, kD, kD, kD / 128, 256, kD, 0);

  // h1 = LN(att) -> bf16 (wcp is dead by now; h1bf overlays it)
  ln1_bf16_kernel<<<dim3(kM), dim3(256), 0, stream>>>(att, lng, lnb, h1bf);

  // FF1: a1 = relu(h1 @ W1 + b1) : grid 1024 (32x32), K=1024 (16 steps)
  cast_transpose_kernel<<<dim3(kFF / 32, kD / 32), dim3(32, 32), 0, stream>>>(
      W1, wT, kD, kFF, 1.0f);
  gemm_bt<1, 1><<<dim3(1024), dim3(256), 0, stream>>>(
      h1bf, wT, b1, a1, kM, kFF, kD, kFF / 128, 1024, kD, 0);

  // FF2: ff = a1 @ W2 + b2 : grid 256 (32x8), K=4096 (64 steps), no split
  cast_transpose_kernel<<<dim3(kD / 32, kFF / 32), dim3(32, 32), 0, stream>>>(
      W2, wT, kFF, kD, 1.0f);
  gemm_bt<0, 0><<<dim3(256), dim3(256), 0, stream>>>(
      a1, wT, b2, ff, kM, kD, kFF, kD / 128, 256, kFF, 0);

  // out = LN(h1 + ff)
  ln_fin_kernel<<<dim3(kM), dim3(256), 0, stream>>>(h1bf, ff, lng, lnb, out);
}

// Round 8
// 176.235 us; speedup vs baseline: 1.1054x; 1.1054x over previous
//
#include <hip/hip_runtime.h>

// Problem constants (from reference)
static constexpr int kB = 2, kS = 2048, kD = 1024, kFF = 4096;
static constexpr int kM = kB * kS;  // 4096 token rows
static constexpr size_t MB = 1u << 20;

typedef __attribute__((ext_vector_type(8))) short short8;
typedef __attribute__((ext_vector_type(4))) float f32x4;

__device__ __forceinline__ unsigned short f2bf(float f) {
  union { float f; unsigned int u; } c; c.f = f;
  unsigned int u = c.u;
  unsigned int r = u + 0x7FFFu + ((u >> 16) & 1u);  // RNE
  return (unsigned short)(r >> 16);
}

__device__ __forceinline__ float bf2f(unsigned short b) {
  union { unsigned int u; float f; } c;
  c.u = ((unsigned int)b) << 16;
  return c.f;
}

__device__ __forceinline__ void gload_lds16(const void* g, void* l) {
  __builtin_amdgcn_global_load_lds(
      (const __attribute__((address_space(1))) void*)g,
      (__attribute__((address_space(3))) void*)l, 16, 0, 0);
}

// ---------------- cast fp32 -> bf16 (vectorized) ----------------
__global__ __launch_bounds__(256) void cast_bf16_kernel(
    const float* __restrict__ in, unsigned short* __restrict__ out, int n) {
  int i = (blockIdx.x * 256 + threadIdx.x) * 4;
  if (i >= n) return;
  float4 v = *(const float4*)(in + i);
  ushort4 o;
  o.x = f2bf(v.x); o.y = f2bf(v.y); o.z = f2bf(v.z); o.w = f2bf(v.w);
  *(ushort4*)(out + i) = o;
}

// ------------- cast + transpose: W[K][N] fp32 -> Wt[N][K] bf16 (× scale) -------------
__global__ __launch_bounds__(1024) void cast_transpose_kernel(
    const float* __restrict__ W, unsigned short* __restrict__ Wt,
    int K, int N, float scale) {
  __shared__ float tile[32][33];
  int nb = blockIdx.x * 32, kb = blockIdx.y * 32;
  int tx = threadIdx.x, ty = threadIdx.y;
  tile[ty][tx] = W[(size_t)(kb + ty) * N + (nb + tx)];
  __syncthreads();
  Wt[(size_t)(nb + ty) * K + (kb + tx)] = f2bf(tile[tx][ty] * scale);
}

// --------- parallel GEMV phase 1: partial[b][n] = sum_{f in block b} bv[f]*Wo[f][n] ---
__global__ __launch_bounds__(256) void bias_gemv_part_kernel(
    const float* __restrict__ bv, const float* __restrict__ Wo,
    float* __restrict__ partial) {
  const int b = blockIdx.x, t = threadIdx.x;
  const int c = t * 4;
  float4 acc = {0.f, 0.f, 0.f, 0.f};
#pragma unroll
  for (int r = 0; r < 8; ++r) {
    const int f = b * 8 + r;
    const float s = bv[f];
    float4 w = *(const float4*)(Wo + (size_t)f * 1024 + c);
    acc.x = fmaf(s, w.x, acc.x);
    acc.y = fmaf(s, w.y, acc.y);
    acc.z = fmaf(s, w.z, acc.z);
    acc.w = fmaf(s, w.w, acc.w);
  }
  *(float4*)(partial + (size_t)b * 1024 + c) = acc;
}

// --------- GEMV phase 2: bc[n] = 2048 * sum_b partial[b][n] + bo[n] ---------
__global__ __launch_bounds__(256) void bias_gemv_fin_kernel(
    const float* __restrict__ partial, const float* __restrict__ bo,
    float* __restrict__ bc) {
  const int n = blockIdx.x * 256 + threadIdx.x;
  float acc = 0.0f;
#pragma unroll 8
  for (int b = 0; b < 128; ++b) acc += partial[(size_t)b * 1024 + n];
  bc[n] = 2048.0f * acc + bo[n];
}

// -------- combine 4 fp32 split-K partials of Wc, add identity, cast bf16 --------
__global__ __launch_bounds__(256) void combine_wc_kernel(
    const float* __restrict__ P, unsigned short* __restrict__ Wt) {
  const int i = (blockIdx.x * 256 + threadIdx.x) * 4;  // grid 1024
  const int MN = 1024 * 1024;
  float4 s0 = *(const float4*)(P + i);
  float4 s1 = *(const float4*)(P + MN + i);
  float4 s2 = *(const float4*)(P + 2 * MN + i);
  float4 s3 = *(const float4*)(P + 3 * MN + i);
  const int row = i >> 10, col = i & 1023;
  float v0 = s0.x + s1.x + s2.x + s3.x + (row == col + 0 ? 1.0f : 0.0f);
  float v1 = s0.y + s1.y + s2.y + s3.y + (row == col + 1 ? 1.0f : 0.0f);
  float v2 = s0.z + s1.z + s2.z + s3.z + (row == col + 2 ? 1.0f : 0.0f);
  float v3 = s0.w + s1.w + s2.w + s3.w + (row == col + 3 ? 1.0f : 0.0f);
  ushort4 o; o.x = f2bf(v0); o.y = f2bf(v1); o.z = f2bf(v2); o.w = f2bf(v3);
  *(ushort4*)(Wt + i) = o;
}

// ---------------- GEMM: C[M,N] = A[M,K] @ Bt[N,K]^T (+bias, opt relu, split-K) ----
// 128x128 tile, BK=64, 4 waves (2x2). Single 32KB LDS buffer (m97 structure;
// latency hiding comes from >=2 blocks/CU TLP -- keep grid >= 512!).
// T2 XOR-swizzle (both-sides, rule 21): measured 0 conflicts. T1 XCD swizzle.
template <int OUT_BF16, int RELU>
__global__ __launch_bounds__(256, 4) void gemm_bt(
    const unsigned short* __restrict__ A, const unsigned short* __restrict__ Bt,
    const float* __restrict__ bias, void* __restrict__ Cout,
    int M, int N, int K, int nXtiles, int nTilesPerSplit, int kSplitLen,
    size_t cSplitStride) {
  __shared__ __align__(16) unsigned short sA[128 * 64];
  __shared__ __align__(16) unsigned short sB[128 * 64];
  const int tid = threadIdx.x;
  const int wave = tid >> 6, lane = tid & 63;
  const int wr = wave >> 1, wc = wave & 1;
  const int nwg = gridDim.x;
  const int q = nwg >> 3, r = nwg & 7;
  const int xcd = blockIdx.x & 7, pos = blockIdx.x >> 3;
  const int swz = (xcd < r) ? (xcd * (q + 1) + pos) : (r * (q + 1) + (xcd - r) * q + pos);
  const int split = swz / nTilesPerSplit, rem = swz % nTilesPerSplit;
  const int m0 = (rem / nXtiles) * 128, n0 = (rem % nXtiles) * 128;
  const int kBeg = split * kSplitLen, kEnd = kBeg + kSplitLen;
  const int srow = lane >> 3;
  const int scol = ((lane & 7) ^ srow) * 8;  // pre-swizzled global col (elements)

  f32x4 acc[4][4] = {};

  for (int k0 = kBeg; k0 < kEnd; k0 += 64) {
#pragma unroll
    for (int i = 0; i < 4; ++i) {
      const int chunk = i * 4 + wave;
      const int rr = chunk * 8 + srow;
      gload_lds16(A + (size_t)(m0 + rr) * K + (k0 + scol), &sA[chunk * 512]);
      gload_lds16(Bt + (size_t)(n0 + rr) * K + (k0 + scol), &sB[chunk * 512]);
    }
    __syncthreads();
#pragma unroll
    for (int kk = 0; kk < 64; kk += 32) {
      const int kcol = kk + (lane >> 4) * 8;
      const int kswz = (lane & 7) * 8;
      short8 af[4], bfr[4];
#pragma unroll
      for (int m = 0; m < 4; ++m)
        af[m] = *(const short8*)&sA[(wr * 64 + m * 16 + (lane & 15)) * 64 + (kcol ^ kswz)];
#pragma unroll
      for (int n = 0; n < 4; ++n)
        bfr[n] = *(const short8*)&sB[(wc * 64 + n * 16 + (lane & 15)) * 64 + (kcol ^ kswz)];
#pragma unroll
      for (int m = 0; m < 4; ++m)
#pragma unroll
        for (int n = 0; n < 4; ++n)
          acc[m][n] = __builtin_amdgcn_mfma_f32_16x16x32_bf16(af[m], bfr[n], acc[m][n], 0, 0, 0);
    }
    __syncthreads();
  }

  const int cl = lane & 15, rg = lane >> 4;
  const float* bptr = (split == 0) ? bias : nullptr;
#pragma unroll
  for (int n = 0; n < 4; ++n) {
    const int col = n0 + wc * 64 + n * 16 + cl;
    const float bias_v = bptr ? bptr[col] : 0.0f;
#pragma unroll
    for (int m = 0; m < 4; ++m) {
      const int rbase = m0 + wr * 64 + m * 16 + rg * 4;
#pragma unroll
      for (int j = 0; j < 4; ++j) {
        float v = acc[m][n][j] + bias_v;
        if (RELU) v = fmaxf(v, 0.0f);
        if (OUT_BF16)
          ((unsigned short*)Cout)[(size_t)(rbase + j) * N + col] = f2bf(v);
        else
          ((float*)Cout)[split * cSplitStride + (size_t)(rbase + j) * N + col] = v;
      }
    }
  }
}

// -------- LN over D=1024 of sum of 2 fp32 partials -> bf16 out --------
__global__ __launch_bounds__(256) void ln2_bf16_kernel(
    const float* __restrict__ P, size_t pStr,
    const float* __restrict__ gg, const float* __restrict__ bb,
    unsigned short* __restrict__ Hb) {
  const int row = blockIdx.x, t = threadIdx.x;
  const size_t base = (size_t)row * 1024 + t * 4;
  float4 v0 = *(const float4*)(P + base);
  float4 v1 = *(const float4*)(P + pStr + base);
  float a0 = v0.x + v1.x, a1 = v0.y + v1.y, a2 = v0.z + v1.z, a3 = v0.w + v1.w;
  float s = a0 + a1 + a2 + a3;
  float ss = a0 * a0 + a1 * a1 + a2 * a2 + a3 * a3;
#pragma unroll
  for (int off = 32; off > 0; off >>= 1) {
    s += __shfl_down(s, off);
    ss += __shfl_down(ss, off);
  }
  __shared__ float rs[4], rss[4];
  __shared__ float smean, srstd;
  const int wave = t >> 6, lane = t & 63;
  if (lane == 0) { rs[wave] = s; rss[wave] = ss; }
  __syncthreads();
  if (t == 0) {
    float S1 = rs[0] + rs[1] + rs[2] + rs[3];
    float S2 = rss[0] + rss[1] + rss[2] + rss[3];
    float mean = S1 * (1.0f / 1024.0f);
    float var = S2 * (1.0f / 1024.0f) - mean * mean;
    smean = mean;
    srstd = rsqrtf(var + 1e-5f);
  }
  __syncthreads();
  const float mean = smean, rstd = srstd;
  float4 gv = *(const float4*)(gg + t * 4);
  float4 bv = *(const float4*)(bb + t * 4);
  ushort4 hb;
  hb.x = f2bf((a0 - mean) * rstd * gv.x + bv.x);
  hb.y = f2bf((a1 - mean) * rstd * gv.y + bv.y);
  hb.z = f2bf((a2 - mean) * rstd * gv.z + bv.z);
  hb.w = f2bf((a3 - mean) * rstd * gv.w + bv.w);
  *(ushort4*)(Hb + base) = hb;
}

// -------- LN of (bf16 residual + sum of 4 fp32 partials) -> fp32 out --------
__global__ __launch_bounds__(256) void ln_fin4_kernel(
    const unsigned short* __restrict__ Res, const float* __restrict__ P, size_t pStr,
    const float* __restrict__ gg, const float* __restrict__ bb,
    float* __restrict__ out) {
  const int row = blockIdx.x, t = threadIdx.x;
  const size_t base = (size_t)row * 1024 + t * 4;
  ushort4 rv = *(const ushort4*)(Res + base);
  float4 v0 = *(const float4*)(P + base);
  float4 v1 = *(const float4*)(P + pStr + base);
  float4 v2 = *(const float4*)(P + 2 * pStr + base);
  float4 v3 = *(const float4*)(P + 3 * pStr + base);
  float a0 = bf2f(rv.x) + v0.x + v1.x + v2.x + v3.x;
  float a1 = bf2f(rv.y) + v0.y + v1.y + v2.y + v3.y;
  float a2 = bf2f(rv.z) + v0.z + v1.z + v2.z + v3.z;
  float a3 = bf2f(rv.w) + v0.w + v1.w + v2.w + v3.w;
  float s = a0 + a1 + a2 + a3;
  float ss = a0 * a0 + a1 * a1 + a2 * a2 + a3 * a3;
#pragma unroll
  for (int off = 32; off > 0; off >>= 1) {
    s += __shfl_down(s, off);
    ss += __shfl_down(ss, off);
  }
  __shared__ float rs[4], rss[4];
  __shared__ float smean, srstd;
  const int wave = t >> 6, lane = t & 63;
  if (lane == 0) { rs[wave] = s; rss[wave] = ss; }
  __syncthreads();
  if (t == 0) {
    float S1 = rs[0] + rs[1] + rs[2] + rs[3];
    float S2 = rss[0] + rss[1] + rss[2] + rss[3];
    float mean = S1 * (1.0f / 1024.0f);
    float var = S2 * (1.0f / 1024.0f) - mean * mean;
    smean = mean;
    srstd = rsqrtf(var + 1e-5f);
  }
  __syncthreads();
  const float mean = smean, rstd = srstd;
  float4 gv = *(const float4*)(gg + t * 4);
  float4 bv = *(const float4*)(bb + t * 4);
  float4 ov;
  ov.x = (a0 - mean) * rstd * gv.x + bv.x;
  ov.y = (a1 - mean) * rstd * gv.y + bv.y;
  ov.z = (a2 - mean) * rstd * gv.z + bv.z;
  ov.w = (a3 - mean) * rstd * gv.w + bv.w;
  *(float4*)(out + base) = ov;
}

// ---------------------------------------------------------------------------
// Attention is algebraically dead: softmax over q sums to 1 per (b,h,k) column;
// summed over k -> s_bh == S == 2048 exactly. Folding the residual too:
//   h1  = LN( z @ (I + 2048*Wv@Wo) + (2048*bv@Wo + bo) )
//   out = LN( h1 + relu(h1@W1+b1)@W2 + b2 )
// q, k, mask, x, y, Wq, Wk are all unused.
// ---------------------------------------------------------------------------
extern "C" void kernel_launch(void* const* d_in, const int* in_sizes, int n_in,
                              void* d_out, int out_size, void* d_ws, size_t ws_size,
                              hipStream_t stream) {
  const float* z  = (const float*)d_in[2];
  const float* Wv = (const float*)d_in[8];
  const float* bv = (const float*)d_in[9];
  const float* Wo = (const float*)d_in[10];
  const float* bo = (const float*)d_in[11];
  const float* W1 = (const float*)d_in[12];
  const float* b1 = (const float*)d_in[13];
  const float* W2 = (const float*)d_in[14];
  const float* b2 = (const float*)d_in[15];
  const float* lng = (const float*)d_in[16];
  const float* lnb = (const float*)d_in[17];
  float* out = (float*)d_out;

  char* ws = (char*)d_ws;
  // layout (MB offsets), peak 112MB, all lifetimes checked:
  //   0..32 : zbf(0..8, dead after att) -> a1(0..32, FF1 out, alive to FF2)
  //   32..96: wcp(32..48, dead after combine) -> attP 2x16 (32..64, dead
  //           after LN1) -> ffP 4x16 (32..96, FF2 out, alive to LN2)
  //   96..104: h1bf (LN1 out, alive to LN2)
  //   104..112: WoT(104..106) WvBf(106..108) WcT(108..110) bc(110) bprt(+64K)
  //             -> wT (104..112, W1T then W2T; written after all of the
  //                above are dead)
  unsigned short* zbf  = (unsigned short*)(ws + 0 * MB);
  unsigned short* a1   = (unsigned short*)(ws + 0 * MB);
  float*          wcp  = (float*)(ws + 32 * MB);
  float*          attP = (float*)(ws + 32 * MB);
  float*          ffP  = (float*)(ws + 32 * MB);
  unsigned short* h1bf = (unsigned short*)(ws + 96 * MB);
  unsigned short* WoT  = (unsigned short*)(ws + 104 * MB);
  unsigned short* WvBf = (unsigned short*)(ws + 106 * MB);
  unsigned short* WcT  = (unsigned short*)(ws + 108 * MB);
  float*          bc   = (float*)(ws + 110 * MB);
  float*          bprt = (float*)(ws + 110 * MB + 65536);
  unsigned short* wT   = (unsigned short*)(ws + 104 * MB);

  const int nZ = kM * kD;  // 4194304
  const size_t pStr = (size_t)kM * kD;

  // --- weight prep ---
  cast_transpose_kernel<<<dim3(kD / 32, kD / 32), dim3(32, 32), 0, stream>>>(
      Wo, WoT, kD, kD, (float)kS);                 // WoT[n][f] = 2048*Wo[f][n]
  cast_bf16_kernel<<<dim3(kD * kD / 1024), dim3(256), 0, stream>>>(Wv, WvBf, kD * kD);
  bias_gemv_part_kernel<<<dim3(128), dim3(256), 0, stream>>>(bv, Wo, bprt);
  bias_gemv_fin_kernel<<<dim3(4), dim3(256), 0, stream>>>(bprt, bo, bc);
  cast_bf16_kernel<<<dim3(nZ / 1024), dim3(256), 0, stream>>>(z, zbf, nZ);

  // WcT = (2048*Wv@Wo)^T via split-K x4 (grid 256), combine + I + bf16
  gemm_bt<0, 0><<<dim3(256), dim3(256), 0, stream>>>(
      WoT, WvBf, nullptr, wcp, kD, kD, kD, kD / 128, 64, 256, (size_t)kD * kD);
  combine_wc_kernel<<<dim3(1024), dim3(256), 0, stream>>>(wcp, WcT);

  // attP = z @ (I+Wc) + bc : split-K x2 (grid 512, 2 blocks/CU, K=8 steps each)
  gemm_bt<0, 0><<<dim3(512), dim3(256), 0, stream>>>(
      zbf, WcT, bc, attP, kM, kD, kD, kD / 128, 256, 512, pStr);

  // h1 = LN(attP0 + attP1) -> bf16
  ln2_bf16_kernel<<<dim3(kM), dim3(256), 0, stream>>>(attP, pStr, lng, lnb, h1bf);

  // FF1: a1 = relu(h1 @ W1 + b1) : grid 1024 (4 blocks/CU), K=16 steps
  cast_transpose_kernel<<<dim3(kFF / 32, kD / 32), dim3(32, 32), 0, stream>>>(
      W1, wT, kD, kFF, 1.0f);
  gemm_bt<1, 1><<<dim3(1024), dim3(256), 0, stream>>>(
      h1bf, wT, b1, a1, kM, kFF, kD, kFF / 128, 1024, kD, 0);

  // FF2: ffP = a1 @ W2 + b2 : split-K x4 (grid 1024, 4 blocks/CU, K=16 steps)
  cast_transpose_kernel<<<dim3(kD / 32, kFF / 32), dim3(32, 32), 0, stream>>>(
      W2, wT, kFF, kD, 1.0f);
  gemm_bt<0, 0><<<dim3(1024), dim3(256), 0, stream>>>(
      a1, wT, b2, ffP, kM, kD, kFF, kD / 128, 256, kFF / 4, pStr);

  // out = LN(h1 + ffP0..3)
  ln_fin4_kernel<<<dim3(kM), dim3(256), 0, stream>>>(h1bf, ffP, pStr, lng, lnb, out);
}

// Round 9
// 169.319 us; speedup vs baseline: 1.1506x; 1.0408x over previous
//
#include <hip/hip_runtime.h>

// Problem constants (from reference)
static constexpr int kB = 2, kS = 2048, kD = 1024, kFF = 4096;
static constexpr int kM = kB * kS;  // 4096 token rows
static constexpr size_t MB = 1u << 20;

typedef __attribute__((ext_vector_type(8))) short short8;
typedef __attribute__((ext_vector_type(4))) float f32x4;

__device__ __forceinline__ unsigned short f2bf(float f) {
  union { float f; unsigned int u; } c; c.f = f;
  unsigned int u = c.u;
  unsigned int r = u + 0x7FFFu + ((u >> 16) & 1u);  // RNE
  return (unsigned short)(r >> 16);
}

__device__ __forceinline__ float bf2f(unsigned short b) {
  union { unsigned int u; float f; } c;
  c.u = ((unsigned int)b) << 16;
  return c.f;
}

__device__ __forceinline__ void gload_lds16(const void* g, void* l) {
  __builtin_amdgcn_global_load_lds(
      (const __attribute__((address_space(1))) void*)g,
      (__attribute__((address_space(3))) void*)l, 16, 0, 0);
}

// ---------------- cast fp32 -> bf16 (vectorized) ----------------
__global__ __launch_bounds__(256) void cast_bf16_kernel(
    const float* __restrict__ in, unsigned short* __restrict__ out, int n) {
  int i = (blockIdx.x * 256 + threadIdx.x) * 4;
  if (i >= n) return;
  float4 v = *(const float4*)(in + i);
  ushort4 o;
  o.x = f2bf(v.x); o.y = f2bf(v.y); o.z = f2bf(v.z); o.w = f2bf(v.w);
  *(ushort4*)(out + i) = o;
}

// ------------- cast + transpose: W[K][N] fp32 -> Wt[N][K] bf16 (× scale) -------------
__global__ __launch_bounds__(1024) void cast_transpose_kernel(
    const float* __restrict__ W, unsigned short* __restrict__ Wt,
    int K, int N, float scale) {
  __shared__ float tile[32][33];
  int nb = blockIdx.x * 32, kb = blockIdx.y * 32;
  int tx = threadIdx.x, ty = threadIdx.y;
  tile[ty][tx] = W[(size_t)(kb + ty) * N + (nb + tx)];
  __syncthreads();
  Wt[(size_t)(nb + ty) * K + (kb + tx)] = f2bf(tile[tx][ty] * scale);
}

// --------- parallel GEMV phase 1: partial[b][n] = sum_{f in block b} bv[f]*Wo[f][n] ---
__global__ __launch_bounds__(256) void bias_gemv_part_kernel(
    const float* __restrict__ bv, const float* __restrict__ Wo,
    float* __restrict__ partial) {
  const int b = blockIdx.x, t = threadIdx.x;
  const int c = t * 4;
  float4 acc = {0.f, 0.f, 0.f, 0.f};
#pragma unroll
  for (int r = 0; r < 8; ++r) {
    const int f = b * 8 + r;
    const float s = bv[f];
    float4 w = *(const float4*)(Wo + (size_t)f * 1024 + c);
    acc.x = fmaf(s, w.x, acc.x);
    acc.y = fmaf(s, w.y, acc.y);
    acc.z = fmaf(s, w.z, acc.z);
    acc.w = fmaf(s, w.w, acc.w);
  }
  *(float4*)(partial + (size_t)b * 1024 + c) = acc;
}

// --------- GEMV phase 2: bc[n] = 2048 * sum_b partial[b][n] + bo[n] ---------
__global__ __launch_bounds__(256) void bias_gemv_fin_kernel(
    const float* __restrict__ partial, const float* __restrict__ bo,
    float* __restrict__ bc) {
  const int n = blockIdx.x * 256 + threadIdx.x;
  float acc = 0.0f;
#pragma unroll 8
  for (int b = 0; b < 128; ++b) acc += partial[(size_t)b * 1024 + n];
  bc[n] = 2048.0f * acc + bo[n];
}

// -------- combine 4 fp32 split-K partials of Wc, add identity, cast bf16 --------
__global__ __launch_bounds__(256) void combine_wc_kernel(
    const float* __restrict__ P, unsigned short* __restrict__ Wt) {
  const int i = (blockIdx.x * 256 + threadIdx.x) * 4;  // grid 1024
  const int MN = 1024 * 1024;
  float4 s0 = *(const float4*)(P + i);
  float4 s1 = *(const float4*)(P + MN + i);
  float4 s2 = *(const float4*)(P + 2 * MN + i);
  float4 s3 = *(const float4*)(P + 3 * MN + i);
  const int row = i >> 10, col = i & 1023;
  float v0 = s0.x + s1.x + s2.x + s3.x + (row == col + 0 ? 1.0f : 0.0f);
  float v1 = s0.y + s1.y + s2.y + s3.y + (row == col + 1 ? 1.0f : 0.0f);
  float v2 = s0.z + s1.z + s2.z + s3.z + (row == col + 2 ? 1.0f : 0.0f);
  float v3 = s0.w + s1.w + s2.w + s3.w + (row == col + 3 ? 1.0f : 0.0f);
  ushort4 o; o.x = f2bf(v0); o.y = f2bf(v1); o.z = f2bf(v2); o.w = f2bf(v3);
  *(ushort4*)(Wt + i) = o;
}

// ---------------- GEMM: C[M,N] = A[M,K] @ Bt[N,K]^T (+bias, opt relu, split-K) ----
// 128x128 tile, BK=64, 4 waves (2x2). Single 32KB LDS buffer (m97 structure;
// latency hiding from >=2 blocks/CU TLP -- keep grid >= 512 for big GEMMs).
// T2 XOR-swizzle (both-sides, rule 21): measured 0 conflicts. T1 XCD swizzle.
// cStride: element stride between split partial outputs (0 if unsplit).
template <int OUT_BF16, int RELU>
__global__ __launch_bounds__(256, 4) void gemm_bt(
    const unsigned short* __restrict__ A, const unsigned short* __restrict__ Bt,
    const float* __restrict__ bias, void* __restrict__ Cout,
    int M, int N, int K, int nXtiles, int nTilesPerSplit, int kSplitLen,
    size_t cStride) {
  __shared__ __align__(16) unsigned short sA[128 * 64];
  __shared__ __align__(16) unsigned short sB[128 * 64];
  const int tid = threadIdx.x;
  const int wave = tid >> 6, lane = tid & 63;
  const int wr = wave >> 1, wc = wave & 1;
  const int nwg = gridDim.x;
  const int q = nwg >> 3, r = nwg & 7;
  const int xcd = blockIdx.x & 7, pos = blockIdx.x >> 3;
  const int swz = (xcd < r) ? (xcd * (q + 1) + pos) : (r * (q + 1) + (xcd - r) * q + pos);
  const int split = swz / nTilesPerSplit, rem = swz % nTilesPerSplit;
  const int m0 = (rem / nXtiles) * 128, n0 = (rem % nXtiles) * 128;
  const int kBeg = split * kSplitLen, kEnd = kBeg + kSplitLen;
  const int srow = lane >> 3;
  const int scol = ((lane & 7) ^ srow) * 8;  // pre-swizzled global col (elements)

  f32x4 acc[4][4] = {};

  for (int k0 = kBeg; k0 < kEnd; k0 += 64) {
#pragma unroll
    for (int i = 0; i < 4; ++i) {
      const int chunk = i * 4 + wave;
      const int rr = chunk * 8 + srow;
      gload_lds16(A + (size_t)(m0 + rr) * K + (k0 + scol), &sA[chunk * 512]);
      gload_lds16(Bt + (size_t)(n0 + rr) * K + (k0 + scol), &sB[chunk * 512]);
    }
    __syncthreads();
#pragma unroll
    for (int kk = 0; kk < 64; kk += 32) {
      const int kcol = kk + (lane >> 4) * 8;
      const int kswz = (lane & 7) * 8;
      short8 af[4], bfr[4];
#pragma unroll
      for (int m = 0; m < 4; ++m)
        af[m] = *(const short8*)&sA[(wr * 64 + m * 16 + (lane & 15)) * 64 + (kcol ^ kswz)];
#pragma unroll
      for (int n = 0; n < 4; ++n)
        bfr[n] = *(const short8*)&sB[(wc * 64 + n * 16 + (lane & 15)) * 64 + (kcol ^ kswz)];
#pragma unroll
      for (int m = 0; m < 4; ++m)
#pragma unroll
        for (int n = 0; n < 4; ++n)
          acc[m][n] = __builtin_amdgcn_mfma_f32_16x16x32_bf16(af[m], bfr[n], acc[m][n], 0, 0, 0);
    }
    __syncthreads();
  }

  const int cl = lane & 15, rg = lane >> 4;
  const float* bptr = (split == 0) ? bias : nullptr;
#pragma unroll
  for (int n = 0; n < 4; ++n) {
    const int col = n0 + wc * 64 + n * 16 + cl;
    const float bias_v = bptr ? bptr[col] : 0.0f;
#pragma unroll
    for (int m = 0; m < 4; ++m) {
      const int rbase = m0 + wr * 64 + m * 16 + rg * 4;
#pragma unroll
      for (int j = 0; j < 4; ++j) {
        float v = acc[m][n][j] + bias_v;
        if (RELU) v = fmaxf(v, 0.0f);
        const size_t idx = split * cStride + (size_t)(rbase + j) * N + col;
        if (OUT_BF16)
          ((unsigned short*)Cout)[idx] = f2bf(v);
        else
          ((float*)Cout)[idx] = v;
      }
    }
  }
}

// -------- LN over D=1024 of sum of 2 bf16 partials -> bf16 out --------
__global__ __launch_bounds__(256) void ln2_bf16_kernel(
    const unsigned short* __restrict__ P, size_t pStr,
    const float* __restrict__ gg, const float* __restrict__ bb,
    unsigned short* __restrict__ Hb) {
  const int row = blockIdx.x, t = threadIdx.x;
  const size_t base = (size_t)row * 1024 + t * 4;
  ushort4 v0 = *(const ushort4*)(P + base);
  ushort4 v1 = *(const ushort4*)(P + pStr + base);
  float a0 = bf2f(v0.x) + bf2f(v1.x);
  float a1 = bf2f(v0.y) + bf2f(v1.y);
  float a2 = bf2f(v0.z) + bf2f(v1.z);
  float a3 = bf2f(v0.w) + bf2f(v1.w);
  float s = a0 + a1 + a2 + a3;
  float ss = a0 * a0 + a1 * a1 + a2 * a2 + a3 * a3;
#pragma unroll
  for (int off = 32; off > 0; off >>= 1) {
    s += __shfl_down(s, off);
    ss += __shfl_down(ss, off);
  }
  __shared__ float rs[4], rss[4];
  __shared__ float smean, srstd;
  const int wave = t >> 6, lane = t & 63;
  if (lane == 0) { rs[wave] = s; rss[wave] = ss; }
  __syncthreads();
  if (t == 0) {
    float S1 = rs[0] + rs[1] + rs[2] + rs[3];
    float S2 = rss[0] + rss[1] + rss[2] + rss[3];
    float mean = S1 * (1.0f / 1024.0f);
    float var = S2 * (1.0f / 1024.0f) - mean * mean;
    smean = mean;
    srstd = rsqrtf(var + 1e-5f);
  }
  __syncthreads();
  const float mean = smean, rstd = srstd;
  float4 gv = *(const float4*)(gg + t * 4);
  float4 bv = *(const float4*)(bb + t * 4);
  ushort4 hb;
  hb.x = f2bf((a0 - mean) * rstd * gv.x + bv.x);
  hb.y = f2bf((a1 - mean) * rstd * gv.y + bv.y);
  hb.z = f2bf((a2 - mean) * rstd * gv.z + bv.z);
  hb.w = f2bf((a3 - mean) * rstd * gv.w + bv.w);
  *(ushort4*)(Hb + base) = hb;
}

// -------- LN of (bf16 residual + sum of 4 bf16 partials) -> fp32 out --------
__global__ __launch_bounds__(256) void ln_fin4_kernel(
    const unsigned short* __restrict__ Res, const unsigned short* __restrict__ P,
    size_t pStr, const float* __restrict__ gg, const float* __restrict__ bb,
    float* __restrict__ out) {
  const int row = blockIdx.x, t = threadIdx.x;
  const size_t base = (size_t)row * 1024 + t * 4;
  ushort4 rv = *(const ushort4*)(Res + base);
  ushort4 v0 = *(const ushort4*)(P + base);
  ushort4 v1 = *(const ushort4*)(P + pStr + base);
  ushort4 v2 = *(const ushort4*)(P + 2 * pStr + base);
  ushort4 v3 = *(const ushort4*)(P + 3 * pStr + base);
  float a0 = bf2f(rv.x) + bf2f(v0.x) + bf2f(v1.x) + bf2f(v2.x) + bf2f(v3.x);
  float a1 = bf2f(rv.y) + bf2f(v0.y) + bf2f(v1.y) + bf2f(v2.y) + bf2f(v3.y);
  float a2 = bf2f(rv.z) + bf2f(v0.z) + bf2f(v1.z) + bf2f(v2.z) + bf2f(v3.z);
  float a3 = bf2f(rv.w) + bf2f(v0.w) + bf2f(v1.w) + bf2f(v2.w) + bf2f(v3.w);
  float s = a0 + a1 + a2 + a3;
  float ss = a0 * a0 + a1 * a1 + a2 * a2 + a3 * a3;
#pragma unroll
  for (int off = 32; off > 0; off >>= 1) {
    s += __shfl_down(s, off);
    ss += __shfl_down(ss, off);
  }
  __shared__ float rs[4], rss[4];
  __shared__ float smean, srstd;
  const int wave = t >> 6, lane = t & 63;
  if (lane == 0) { rs[wave] = s; rss[wave] = ss; }
  __syncthreads();
  if (t == 0) {
    float S1 = rs[0] + rs[1] + rs[2] + rs[3];
    float S2 = rss[0] + rss[1] + rss[2] + rss[3];
    float mean = S1 * (1.0f / 1024.0f);
    float var = S2 * (1.0f / 1024.0f) - mean * mean;
    smean = mean;
    srstd = rsqrtf(var + 1e-5f);
  }
  __syncthreads();
  const float mean = smean, rstd = srstd;
  float4 gv = *(const float4*)(gg + t * 4);
  float4 bv = *(const float4*)(bb + t * 4);
  float4 ov;
  ov.x = (a0 - mean) * rstd * gv.x + bv.x;
  ov.y = (a1 - mean) * rstd * gv.y + bv.y;
  ov.z = (a2 - mean) * rstd * gv.z + bv.z;
  ov.w = (a3 - mean) * rstd * gv.w + bv.w;
  *(float4*)(out + base) = ov;
}

// ---------------------------------------------------------------------------
// Attention is algebraically dead: softmax over q sums to 1 per (b,h,k) column;
// summed over k -> s_bh == S == 2048 exactly. Folding the residual too:
//   h1  = LN( z @ (I + 2048*Wv@Wo) + (2048*bv@Wo + bo) )
//   out = LN( h1 + relu(h1@W1+b1)@W2 + b2 )
// q, k, mask, x, y, Wq, Wk are all unused.
// ---------------------------------------------------------------------------
extern "C" void kernel_launch(void* const* d_in, const int* in_sizes, int n_in,
                              void* d_out, int out_size, void* d_ws, size_t ws_size,
                              hipStream_t stream) {
  const float* z  = (const float*)d_in[2];
  const float* Wv = (const float*)d_in[8];
  const float* bv = (const float*)d_in[9];
  const float* Wo = (const float*)d_in[10];
  const float* bo = (const float*)d_in[11];
  const float* W1 = (const float*)d_in[12];
  const float* b1 = (const float*)d_in[13];
  const float* W2 = (const float*)d_in[14];
  const float* b2 = (const float*)d_in[15];
  const float* lng = (const float*)d_in[16];
  const float* lnb = (const float*)d_in[17];
  float* out = (float*)d_out;

  char* ws = (char*)d_ws;
  // layout (MB offsets), peak 112MB, lifetimes checked:
  //   0..32 : zbf(0..8, dead after att) -> a1(0..32, FF1 out, alive to FF2)
  //   32..96: wcp fp32 4x4MB? (32..48, dead after combine)
  //           -> attP bf16 2x8MB (32..48, dead after LN1)
  //           -> ffP bf16 4x8MB (32..64, FF2 out, alive to LN2)
  //   96..104: h1bf (LN1 out, alive to LN2)
  //   104..112: WoT(104..106) WvBf(106..108) WcT(108..110) bc(110) bprt(+64K)
  //             -> wT (104..112, W1T then W2T; written after those are dead)
  unsigned short* zbf  = (unsigned short*)(ws + 0 * MB);
  unsigned short* a1   = (unsigned short*)(ws + 0 * MB);
  float*          wcp  = (float*)(ws + 32 * MB);
  unsigned short* attP = (unsigned short*)(ws + 32 * MB);
  unsigned short* ffP  = (unsigned short*)(ws + 32 * MB);
  unsigned short* h1bf = (unsigned short*)(ws + 96 * MB);
  unsigned short* WoT  = (unsigned short*)(ws + 104 * MB);
  unsigned short* WvBf = (unsigned short*)(ws + 106 * MB);
  unsigned short* WcT  = (unsigned short*)(ws + 108 * MB);
  float*          bc   = (float*)(ws + 110 * MB);
  float*          bprt = (float*)(ws + 110 * MB + 65536);
  unsigned short* wT   = (unsigned short*)(ws + 104 * MB);

  const int nZ = kM * kD;  // 4194304
  const size_t pStr = (size_t)kM * kD;  // elements per partial

  // --- weight prep ---
  cast_transpose_kernel<<<dim3(kD / 32, kD / 32), dim3(32, 32), 0, stream>>>(
      Wo, WoT, kD, kD, (float)kS);                 // WoT[n][f] = 2048*Wo[f][n]
  cast_bf16_kernel<<<dim3(kD * kD / 1024), dim3(256), 0, stream>>>(Wv, WvBf, kD * kD);
  bias_gemv_part_kernel<<<dim3(128), dim3(256), 0, stream>>>(bv, Wo, bprt);
  bias_gemv_fin_kernel<<<dim3(4), dim3(256), 0, stream>>>(bprt, bo, bc);
  cast_bf16_kernel<<<dim3(nZ / 1024), dim3(256), 0, stream>>>(z, zbf, nZ);

  // WcT = (2048*Wv@Wo)^T via split-K x4 (grid 256, fp32 partials), combine+I+bf16
  gemm_bt<0, 0><<<dim3(256), dim3(256), 0, stream>>>(
      WoT, WvBf, nullptr, wcp, kD, kD, kD, kD / 128, 64, 256, (size_t)kD * kD);
  combine_wc_kernel<<<dim3(1024), dim3(256), 0, stream>>>(wcp, WcT);

  // attP = z @ (I+Wc) + bc : split-K x2 (grid 512, 2 blocks/CU), bf16 partials
  gemm_bt<1, 0><<<dim3(512), dim3(256), 0, stream>>>(
      zbf, WcT, bc, attP, kM, kD, kD, kD / 128, 256, 512, pStr);

  // h1 = LN(attP0 + attP1) -> bf16
  ln2_bf16_kernel<<<dim3(kM), dim3(256), 0, stream>>>(attP, pStr, lng, lnb, h1bf);

  // FF1: a1 = relu(h1 @ W1 + b1) : grid 1024 (4 blocks/CU), K=16 steps
  cast_transpose_kernel<<<dim3(kFF / 32, kD / 32), dim3(32, 32), 0, stream>>>(
      W1, wT, kD, kFF, 1.0f);
  gemm_bt<1, 1><<<dim3(1024), dim3(256), 0, stream>>>(
      h1bf, wT, b1, a1, kM, kFF, kD, kFF / 128, 1024, kD, 0);

  // FF2: ffP = a1 @ W2 + b2 : split-K x4 (grid 1024, 4 blocks/CU), bf16 partials
  cast_transpose_kernel<<<dim3(kD / 32, kFF / 32), dim3(32, 32), 0, stream>>>(
      W2, wT, kFF, kD, 1.0f);
  gemm_bt<1, 0><<<dim3(1024), dim3(256), 0, stream>>>(
      a1, wT, b2, ffP, kM, kD, kFF, kD / 128, 256, kFF / 4, pStr);

  // out = LN(h1 + ffP0..3)
  ln_fin4_kernel<<<dim3(kM), dim3(256), 0, stream>>>(h1bf, ffP, pStr, lng, lnb, out);
}

// Round 10
// 165.763 us; speedup vs baseline: 1.1753x; 1.0215x over previous
//
#include <hip/hip_runtime.h>

// Problem constants (from reference)
static constexpr int kB = 2, kS = 2048, kD = 1024, kFF = 4096;
static constexpr int kM = kB * kS;  // 4096 token rows
static constexpr size_t MB = 1u << 20;

typedef __attribute__((ext_vector_type(8))) short short8;
typedef __attribute__((ext_vector_type(4))) float f32x4;

__device__ __forceinline__ unsigned short f2bf(float f) {
  union { float f; unsigned int u; } c; c.f = f;
  unsigned int u = c.u;
  unsigned int r = u + 0x7FFFu + ((u >> 16) & 1u);  // RNE
  return (unsigned short)(r >> 16);
}

__device__ __forceinline__ float bf2f(unsigned short b) {
  union { unsigned int u; float f; } c;
  c.u = ((unsigned int)b) << 16;
  return c.f;
}

__device__ __forceinline__ void gload_lds16(const void* g, void* l) {
  __builtin_amdgcn_global_load_lds(
      (const __attribute__((address_space(1))) void*)g,
      (__attribute__((address_space(3))) void*)l, 16, 0, 0);
}

// ---------------- cast fp32 -> bf16 (vectorized) ----------------
__global__ __launch_bounds__(256) void cast_bf16_kernel(
    const float* __restrict__ in, unsigned short* __restrict__ out, int n) {
  int i = (blockIdx.x * 256 + threadIdx.x) * 4;
  if (i >= n) return;
  float4 v = *(const float4*)(in + i);
  ushort4 o;
  o.x = f2bf(v.x); o.y = f2bf(v.y); o.z = f2bf(v.z); o.w = f2bf(v.w);
  *(ushort4*)(out + i) = o;
}

// ------------- cast + transpose: W[K][N] fp32 -> Wt[N][K] bf16 (× scale) -------------
__global__ __launch_bounds__(1024) void cast_transpose_kernel(
    const float* __restrict__ W, unsigned short* __restrict__ Wt,
    int K, int N, float scale) {
  __shared__ float tile[32][33];
  int nb = blockIdx.x * 32, kb = blockIdx.y * 32;
  int tx = threadIdx.x, ty = threadIdx.y;
  tile[ty][tx] = W[(size_t)(kb + ty) * N + (nb + tx)];
  __syncthreads();
  Wt[(size_t)(nb + ty) * K + (kb + tx)] = f2bf(tile[tx][ty] * scale);
}

// --------- parallel GEMV phase 1: partial[b][n] = sum_{f in block b} bv[f]*Wo[f][n] ---
__global__ __launch_bounds__(256) void bias_gemv_part_kernel(
    const float* __restrict__ bv, const float* __restrict__ Wo,
    float* __restrict__ partial) {
  const int b = blockIdx.x, t = threadIdx.x;
  const int c = t * 4;
  float4 acc = {0.f, 0.f, 0.f, 0.f};
#pragma unroll
  for (int r = 0; r < 8; ++r) {
    const int f = b * 8 + r;
    const float s = bv[f];
    float4 w = *(const float4*)(Wo + (size_t)f * 1024 + c);
    acc.x = fmaf(s, w.x, acc.x);
    acc.y = fmaf(s, w.y, acc.y);
    acc.z = fmaf(s, w.z, acc.z);
    acc.w = fmaf(s, w.w, acc.w);
  }
  *(float4*)(partial + (size_t)b * 1024 + c) = acc;
}

// --------- GEMV phase 2: bc[n] = 2048 * sum_b partial[b][n] + bo[n] ---------
__global__ __launch_bounds__(256) void bias_gemv_fin_kernel(
    const float* __restrict__ partial, const float* __restrict__ bo,
    float* __restrict__ bc) {
  const int n = blockIdx.x * 256 + threadIdx.x;
  float acc = 0.0f;
#pragma unroll 8
  for (int b = 0; b < 128; ++b) acc += partial[(size_t)b * 1024 + n];
  bc[n] = 2048.0f * acc + bo[n];
}

// -------- combine 4 fp32 split-K partials of Wc, add identity, cast bf16 --------
__global__ __launch_bounds__(256) void combine_wc_kernel(
    const float* __restrict__ P, unsigned short* __restrict__ Wt) {
  const int i = (blockIdx.x * 256 + threadIdx.x) * 4;  // grid 1024
  const int MN = 1024 * 1024;
  float4 s0 = *(const float4*)(P + i);
  float4 s1 = *(const float4*)(P + MN + i);
  float4 s2 = *(const float4*)(P + 2 * MN + i);
  float4 s3 = *(const float4*)(P + 3 * MN + i);
  const int row = i >> 10, col = i & 1023;
  float v0 = s0.x + s1.x + s2.x + s3.x + (row == col + 0 ? 1.0f : 0.0f);
  float v1 = s0.y + s1.y + s2.y + s3.y + (row == col + 1 ? 1.0f : 0.0f);
  float v2 = s0.z + s1.z + s2.z + s3.z + (row == col + 2 ? 1.0f : 0.0f);
  float v3 = s0.w + s1.w + s2.w + s3.w + (row == col + 3 ? 1.0f : 0.0f);
  ushort4 o; o.x = f2bf(v0); o.y = f2bf(v1); o.z = f2bf(v2); o.w = f2bf(v3);
  *(ushort4*)(Wt + i) = o;
}

// ---------------- GEMM: C[M,N] = A[M,K] @ Bt[N,K]^T (+bias, opt relu, split-K) ----
// 128x128 tile, BK=64, 4 waves (2x2). Single 32KB LDS buffer (m97 structure;
// latency hiding from >=2 blocks/CU TLP). T2 XOR-swizzle: measured 0 conflicts.
// XCD mapping (refined T1): each XCD (b%8) owns square-ish (cr x cc) tile
// chunks so its concurrent L2 working set is minimized (row-major strips made
// each XCD re-fetch all of B from HBM: FETCH 59MB vs 16MB ideal in r9).
// Requires (nwg/8) % (cr*cc) == 0; bijective by construction.
template <int OUT_BF16, int RELU>
__global__ __launch_bounds__(256, 4) void gemm_bt(
    const unsigned short* __restrict__ A, const unsigned short* __restrict__ Bt,
    const float* __restrict__ bias, void* __restrict__ Cout,
    int M, int N, int K, int nXtiles, int nTilesPerSplit, int kSplitLen,
    size_t cStride, int cr, int cc) {
  __shared__ __align__(16) unsigned short sA[128 * 64];
  __shared__ __align__(16) unsigned short sB[128 * 64];
  const int tid = threadIdx.x;
  const int wave = tid >> 6, lane = tid & 63;
  const int wr = wave >> 1, wc = wave & 1;

  // super-chunk XCD decomposition
  const int x = blockIdx.x & 7, j = blockIdx.x >> 3;
  const int bpc = cr * cc;
  const int chunkIdx = x + 8 * (j / bpc);
  const int w = j % bpc;
  const int chunksPerSplit = nTilesPerSplit / bpc;
  const int split = chunkIdx / chunksPerSplit;
  const int cL = chunkIdx % chunksPerSplit;
  const int cpr = nXtiles / cc;  // chunks per tile-row band
  const int m0 = ((cL / cpr) * cr + w / cc) * 128;
  const int n0 = ((cL % cpr) * cc + w % cc) * 128;
  const int kBeg = split * kSplitLen, kEnd = kBeg + kSplitLen;

  const int srow = lane >> 3;
  const int scol = ((lane & 7) ^ srow) * 8;  // pre-swizzled global col (elements)

  f32x4 acc[4][4] = {};

  for (int k0 = kBeg; k0 < kEnd; k0 += 64) {
#pragma unroll
    for (int i = 0; i < 4; ++i) {
      const int chunk = i * 4 + wave;
      const int rr = chunk * 8 + srow;
      gload_lds16(A + (size_t)(m0 + rr) * K + (k0 + scol), &sA[chunk * 512]);
      gload_lds16(Bt + (size_t)(n0 + rr) * K + (k0 + scol), &sB[chunk * 512]);
    }
    __syncthreads();
#pragma unroll
    for (int kk = 0; kk < 64; kk += 32) {
      const int kcol = kk + (lane >> 4) * 8;
      const int kswz = (lane & 7) * 8;
      short8 af[4], bfr[4];
#pragma unroll
      for (int m = 0; m < 4; ++m)
        af[m] = *(const short8*)&sA[(wr * 64 + m * 16 + (lane & 15)) * 64 + (kcol ^ kswz)];
#pragma unroll
      for (int n = 0; n < 4; ++n)
        bfr[n] = *(const short8*)&sB[(wc * 64 + n * 16 + (lane & 15)) * 64 + (kcol ^ kswz)];
#pragma unroll
      for (int m = 0; m < 4; ++m)
#pragma unroll
        for (int n = 0; n < 4; ++n)
          acc[m][n] = __builtin_amdgcn_mfma_f32_16x16x32_bf16(af[m], bfr[n], acc[m][n], 0, 0, 0);
    }
    __syncthreads();
  }

  const int cl = lane & 15, rg = lane >> 4;
  const float* bptr = (split == 0) ? bias : nullptr;
#pragma unroll
  for (int n = 0; n < 4; ++n) {
    const int col = n0 + wc * 64 + n * 16 + cl;
    const float bias_v = bptr ? bptr[col] : 0.0f;
#pragma unroll
    for (int m = 0; m < 4; ++m) {
      const int rbase = m0 + wr * 64 + m * 16 + rg * 4;
#pragma unroll
      for (int j2 = 0; j2 < 4; ++j2) {
        float v = acc[m][n][j2] + bias_v;
        if (RELU) v = fmaxf(v, 0.0f);
        const size_t idx = split * cStride + (size_t)(rbase + j2) * N + col;
        if (OUT_BF16)
          ((unsigned short*)Cout)[idx] = f2bf(v);
        else
          ((float*)Cout)[idx] = v;
      }
    }
  }
}

// -------- LN over D=1024 of sum of 2 bf16 partials -> bf16 out --------
__global__ __launch_bounds__(256) void ln2_bf16_kernel(
    const unsigned short* __restrict__ P, size_t pStr,
    const float* __restrict__ gg, const float* __restrict__ bb,
    unsigned short* __restrict__ Hb) {
  const int row = blockIdx.x, t = threadIdx.x;
  const size_t base = (size_t)row * 1024 + t * 4;
  ushort4 v0 = *(const ushort4*)(P + base);
  ushort4 v1 = *(const ushort4*)(P + pStr + base);
  float a0 = bf2f(v0.x) + bf2f(v1.x);
  float a1 = bf2f(v0.y) + bf2f(v1.y);
  float a2 = bf2f(v0.z) + bf2f(v1.z);
  float a3 = bf2f(v0.w) + bf2f(v1.w);
  float s = a0 + a1 + a2 + a3;
  float ss = a0 * a0 + a1 * a1 + a2 * a2 + a3 * a3;
#pragma unroll
  for (int off = 32; off > 0; off >>= 1) {
    s += __shfl_down(s, off);
    ss += __shfl_down(ss, off);
  }
  __shared__ float rs[4], rss[4];
  __shared__ float smean, srstd;
  const int wave = t >> 6, lane = t & 63;
  if (lane == 0) { rs[wave] = s; rss[wave] = ss; }
  __syncthreads();
  if (t == 0) {
    float S1 = rs[0] + rs[1] + rs[2] + rs[3];
    float S2 = rss[0] + rss[1] + rss[2] + rss[3];
    float mean = S1 * (1.0f / 1024.0f);
    float var = S2 * (1.0f / 1024.0f) - mean * mean;
    smean = mean;
    srstd = rsqrtf(var + 1e-5f);
  }
  __syncthreads();
  const float mean = smean, rstd = srstd;
  float4 gv = *(const float4*)(gg + t * 4);
  float4 bv = *(const float4*)(bb + t * 4);
  ushort4 hb;
  hb.x = f2bf((a0 - mean) * rstd * gv.x + bv.x);
  hb.y = f2bf((a1 - mean) * rstd * gv.y + bv.y);
  hb.z = f2bf((a2 - mean) * rstd * gv.z + bv.z);
  hb.w = f2bf((a3 - mean) * rstd * gv.w + bv.w);
  *(ushort4*)(Hb + base) = hb;
}

// -------- LN of (bf16 residual + sum of 4 bf16 partials) -> fp32 out --------
__global__ __launch_bounds__(256) void ln_fin4_kernel(
    const unsigned short* __restrict__ Res, const unsigned short* __restrict__ P,
    size_t pStr, const float* __restrict__ gg, const float* __restrict__ bb,
    float* __restrict__ out) {
  const int row = blockIdx.x, t = threadIdx.x;
  const size_t base = (size_t)row * 1024 + t * 4;
  ushort4 rv = *(const ushort4*)(Res + base);
  ushort4 v0 = *(const ushort4*)(P + base);
  ushort4 v1 = *(const ushort4*)(P + pStr + base);
  ushort4 v2 = *(const ushort4*)(P + 2 * pStr + base);
  ushort4 v3 = *(const ushort4*)(P + 3 * pStr + base);
  float a0 = bf2f(rv.x) + bf2f(v0.x) + bf2f(v1.x) + bf2f(v2.x) + bf2f(v3.x);
  float a1 = bf2f(rv.y) + bf2f(v0.y) + bf2f(v1.y) + bf2f(v2.y) + bf2f(v3.y);
  float a2 = bf2f(rv.z) + bf2f(v0.z) + bf2f(v1.z) + bf2f(v2.z) + bf2f(v3.z);
  float a3 = bf2f(rv.w) + bf2f(v0.w) + bf2f(v1.w) + bf2f(v2.w) + bf2f(v3.w);
  float s = a0 + a1 + a2 + a3;
  float ss = a0 * a0 + a1 * a1 + a2 * a2 + a3 * a3;
#pragma unroll
  for (int off = 32; off > 0; off >>= 1) {
    s += __shfl_down(s, off);
    ss += __shfl_down(ss, off);
  }
  __shared__ float rs[4], rss[4];
  __shared__ float smean, srstd;
  const int wave = t >> 6, lane = t & 63;
  if (lane == 0) { rs[wave] = s; rss[wave] = ss; }
  __syncthreads();
  if (t == 0) {
    float S1 = rs[0] + rs[1] + rs[2] + rs[3];
    float S2 = rss[0] + rss[1] + rss[2] + rss[3];
    float mean = S1 * (1.0f / 1024.0f);
    float var = S2 * (1.0f / 1024.0f) - mean * mean;
    smean = mean;
    srstd = rsqrtf(var + 1e-5f);
  }
  __syncthreads();
  const float mean = smean, rstd = srstd;
  float4 gv = *(const float4*)(gg + t * 4);
  float4 bv = *(const float4*)(bb + t * 4);
  float4 ov;
  ov.x = (a0 - mean) * rstd * gv.x + bv.x;
  ov.y = (a1 - mean) * rstd * gv.y + bv.y;
  ov.z = (a2 - mean) * rstd * gv.z + bv.z;
  ov.w = (a3 - mean) * rstd * gv.w + bv.w;
  *(float4*)(out + base) = ov;
}

// ---------------------------------------------------------------------------
// Attention is algebraically dead: softmax over q sums to 1 per (b,h,k) column;
// summed over k -> s_bh == S == 2048 exactly. Folding the residual too:
//   h1  = LN( z @ (I + 2048*Wv@Wo) + (2048*bv@Wo + bo) )
//   out = LN( h1 + relu(h1@W1+b1)@W2 + b2 )
// q, k, mask, x, y, Wq, Wk are all unused.
// ---------------------------------------------------------------------------
extern "C" void kernel_launch(void* const* d_in, const int* in_sizes, int n_in,
                              void* d_out, int out_size, void* d_ws, size_t ws_size,
                              hipStream_t stream) {
  const float* z  = (const float*)d_in[2];
  const float* Wv = (const float*)d_in[8];
  const float* bv = (const float*)d_in[9];
  const float* Wo = (const float*)d_in[10];
  const float* bo = (const float*)d_in[11];
  const float* W1 = (const float*)d_in[12];
  const float* b1 = (const float*)d_in[13];
  const float* W2 = (const float*)d_in[14];
  const float* b2 = (const float*)d_in[15];
  const float* lng = (const float*)d_in[16];
  const float* lnb = (const float*)d_in[17];
  float* out = (float*)d_out;

  char* ws = (char*)d_ws;
  // layout (MB offsets), peak 112MB, lifetimes checked (same as r9):
  unsigned short* zbf  = (unsigned short*)(ws + 0 * MB);
  unsigned short* a1   = (unsigned short*)(ws + 0 * MB);
  float*          wcp  = (float*)(ws + 32 * MB);
  unsigned short* attP = (unsigned short*)(ws + 32 * MB);
  unsigned short* ffP  = (unsigned short*)(ws + 32 * MB);
  unsigned short* h1bf = (unsigned short*)(ws + 96 * MB);
  unsigned short* WoT  = (unsigned short*)(ws + 104 * MB);
  unsigned short* WvBf = (unsigned short*)(ws + 106 * MB);
  unsigned short* WcT  = (unsigned short*)(ws + 108 * MB);
  float*          bc   = (float*)(ws + 110 * MB);
  float*          bprt = (float*)(ws + 110 * MB + 65536);
  unsigned short* wT   = (unsigned short*)(ws + 104 * MB);

  const int nZ = kM * kD;  // 4194304
  const size_t pStr = (size_t)kM * kD;  // elements per partial

  // --- weight prep ---
  cast_transpose_kernel<<<dim3(kD / 32, kD / 32), dim3(32, 32), 0, stream>>>(
      Wo, WoT, kD, kD, (float)kS);                 // WoT[n][f] = 2048*Wo[f][n]
  cast_bf16_kernel<<<dim3(kD * kD / 1024), dim3(256), 0, stream>>>(Wv, WvBf, kD * kD);
  bias_gemv_part_kernel<<<dim3(128), dim3(256), 0, stream>>>(bv, Wo, bprt);
  bias_gemv_fin_kernel<<<dim3(4), dim3(256), 0, stream>>>(bprt, bo, bc);
  cast_bf16_kernel<<<dim3(nZ / 1024), dim3(256), 0, stream>>>(z, zbf, nZ);

  // WcT = (2048*Wv@Wo)^T via split-K x4 (grid 256, fp32 partials), combine+I+bf16
  gemm_bt<0, 0><<<dim3(256), dim3(256), 0, stream>>>(
      WoT, WvBf, nullptr, wcp, kD, kD, kD, kD / 128, 64, 256, (size_t)kD * kD,
      8, 4);
  combine_wc_kernel<<<dim3(1024), dim3(256), 0, stream>>>(wcp, WcT);

  // attP = z @ (I+Wc) + bc : split-K x2 (grid 512, 2 blocks/CU), bf16 partials
  // chunk 8x8 per XCD: working set ~2MB, L2-resident.
  gemm_bt<1, 0><<<dim3(512), dim3(256), 0, stream>>>(
      zbf, WcT, bc, attP, kM, kD, kD, kD / 128, 256, 512, pStr, 8, 8);

  // h1 = LN(attP0 + attP1) -> bf16
  ln2_bf16_kernel<<<dim3(kM), dim3(256), 0, stream>>>(attP, pStr, lng, lnb, h1bf);

  // FF1: a1 = relu(h1 @ W1 + b1) : grid 1024 (4 blocks/CU), chunk 16x8/XCD (~6MB)
  cast_transpose_kernel<<<dim3(kFF / 32, kD / 32), dim3(32, 32), 0, stream>>>(
      W1, wT, kD, kFF, 1.0f);
  gemm_bt<1, 1><<<dim3(1024), dim3(256), 0, stream>>>(
      h1bf, wT, b1, a1, kM, kFF, kD, kFF / 128, 1024, kD, 0, 16, 8);

  // FF2: ffP = a1 @ W2 + b2 : split-K x4 (grid 1024), chunk 16x8/XCD (~6MB)
  cast_transpose_kernel<<<dim3(kD / 32, kFF / 32), dim3(32, 32), 0, stream>>>(
      W2, wT, kFF, kD, 1.0f);
  gemm_bt<1, 0><<<dim3(1024), dim3(256), 0, stream>>>(
      a1, wT, b2, ffP, kM, kD, kFF, kD / 128, 256, kFF / 4, pStr, 16, 8);

  // out = LN(h1 + ffP0..3)
  ln_fin4_kernel<<<dim3(kM), dim3(256), 0, stream>>>(h1bf, ffP, pStr, lng, lnb, out);
}

// Round 11
// 163.664 us; speedup vs baseline: 1.1903x; 1.0128x over previous
//
#include <hip/hip_runtime.h>

// Problem constants (from reference)
static constexpr int kB = 2, kS = 2048, kD = 1024, kFF = 4096;
static constexpr int kM = kB * kS;  // 4096 token rows
static constexpr size_t MB = 1u << 20;

typedef __attribute__((ext_vector_type(8))) short short8;
typedef __attribute__((ext_vector_type(4))) float f32x4;

__device__ __forceinline__ unsigned short f2bf(float f) {
  union { float f; unsigned int u; } c; c.f = f;
  unsigned int u = c.u;
  unsigned int r = u + 0x7FFFu + ((u >> 16) & 1u);  // RNE
  return (unsigned short)(r >> 16);
}

__device__ __forceinline__ float bf2f(unsigned short b) {
  union { unsigned int u; float f; } c;
  c.u = ((unsigned int)b) << 16;
  return c.f;
}

__device__ __forceinline__ void gload_lds16(const void* g, void* l) {
  __builtin_amdgcn_global_load_lds(
      (const __attribute__((address_space(1))) void*)g,
      (__attribute__((address_space(3))) void*)l, 16, 0, 0);
}

// ---------------- cast fp32 -> bf16 (vectorized) ----------------
__global__ __launch_bounds__(256) void cast_bf16_kernel(
    const float* __restrict__ in, unsigned short* __restrict__ out, int n) {
  int i = (blockIdx.x * 256 + threadIdx.x) * 4;
  if (i >= n) return;
  float4 v = *(const float4*)(in + i);
  ushort4 o;
  o.x = f2bf(v.x); o.y = f2bf(v.y); o.z = f2bf(v.z); o.w = f2bf(v.w);
  *(ushort4*)(out + i) = o;
}

// ------ cast + transpose v2: W[K][N] fp32 -> Wt[N][K] bf16 (x scale) ------
// 64x64 tiles, 256 threads; float4 reads (256B/row-of-16), ushort4 writes
// (128B segments). Replaces the scalar-load 32x32 version.
__global__ __launch_bounds__(256) void cast_transpose64(
    const float* __restrict__ W, unsigned short* __restrict__ Wt,
    int K, int N, float scale, int ntN) {
  __shared__ float tile[64][65];
  const int bid = blockIdx.x;
  const int nb = (bid % ntN) * 64, kb = (bid / ntN) * 64;
  const int tx = threadIdx.x & 15, ty = threadIdx.x >> 4;
#pragma unroll
  for (int p = 0; p < 4; ++p) {
    const int r = ty + 16 * p;
    float4 v = *(const float4*)(W + (size_t)(kb + r) * N + nb + tx * 4);
    tile[r][tx * 4 + 0] = v.x;
    tile[r][tx * 4 + 1] = v.y;
    tile[r][tx * 4 + 2] = v.z;
    tile[r][tx * 4 + 3] = v.w;
  }
  __syncthreads();
#pragma unroll
  for (int p = 0; p < 4; ++p) {
    const int n = ty + 16 * p;
    ushort4 o;
    o.x = f2bf(tile[tx * 4 + 0][n] * scale);
    o.y = f2bf(tile[tx * 4 + 1][n] * scale);
    o.z = f2bf(tile[tx * 4 + 2][n] * scale);
    o.w = f2bf(tile[tx * 4 + 3][n] * scale);
    *(ushort4*)(Wt + (size_t)(nb + n) * K + kb + tx * 4) = o;
  }
}

// --------- parallel GEMV phase 1: partial[b][n] = sum_{f in block b} bv[f]*Wo[f][n] ---
__global__ __launch_bounds__(256) void bias_gemv_part_kernel(
    const float* __restrict__ bv, const float* __restrict__ Wo,
    float* __restrict__ partial) {
  const int b = blockIdx.x, t = threadIdx.x;
  const int c = t * 4;
  float4 acc = {0.f, 0.f, 0.f, 0.f};
#pragma unroll
  for (int r = 0; r < 8; ++r) {
    const int f = b * 8 + r;
    const float s = bv[f];
    float4 w = *(const float4*)(Wo + (size_t)f * 1024 + c);
    acc.x = fmaf(s, w.x, acc.x);
    acc.y = fmaf(s, w.y, acc.y);
    acc.z = fmaf(s, w.z, acc.z);
    acc.w = fmaf(s, w.w, acc.w);
  }
  *(float4*)(partial + (size_t)b * 1024 + c) = acc;
}

// --------- GEMV phase 2: bc[n] = 2048 * sum_b partial[b][n] + bo[n] ---------
__global__ __launch_bounds__(256) void bias_gemv_fin_kernel(
    const float* __restrict__ partial, const float* __restrict__ bo,
    float* __restrict__ bc) {
  const int n = blockIdx.x * 256 + threadIdx.x;
  float acc = 0.0f;
#pragma unroll 8
  for (int b = 0; b < 128; ++b) acc += partial[(size_t)b * 1024 + n];
  bc[n] = 2048.0f * acc + bo[n];
}

// ---------------- GEMM: C[M,N] = A[M,K] @ Bt[N,K]^T (+bias, relu, +I, split-K) ----
// 128x128 tile, BK=64, 4 waves (2x2). Single 32KB LDS buffer (m97 structure;
// latency hiding from >=2 blocks/CU TLP). T2 XOR-swizzle: measured 0 conflicts.
// XCD super-chunk mapping (r10: FETCH 59->26MB). A_F32: stage A from fp32 via
// reg+cvt+ds_write (linear dest = identical LDS layout to gload_lds; source
// col pre-swizzled the same way) -- fuses the z cast into the GEMM.
template <int OUT_BF16, int RELU, int ADD_I, int A_F32>
__global__ __launch_bounds__(256, 4) void gemm_bt(
    const void* __restrict__ A, const unsigned short* __restrict__ Bt,
    const float* __restrict__ bias, void* __restrict__ Cout,
    int M, int N, int K, int nXtiles, int nTilesPerSplit, int kSplitLen,
    size_t cStride, int cr, int cc) {
  __shared__ __align__(16) unsigned short sA[128 * 64];
  __shared__ __align__(16) unsigned short sB[128 * 64];
  const unsigned short* Ab = (const unsigned short*)A;
  const float* Af = (const float*)A;
  const int tid = threadIdx.x;
  const int wave = tid >> 6, lane = tid & 63;
  const int wr = wave >> 1, wc = wave & 1;

  // super-chunk XCD decomposition (bijective; (nwg/8) % (cr*cc) == 0)
  const int x = blockIdx.x & 7, j = blockIdx.x >> 3;
  const int bpc = cr * cc;
  const int chunkIdx = x + 8 * (j / bpc);
  const int w = j % bpc;
  const int chunksPerSplit = nTilesPerSplit / bpc;
  const int split = chunkIdx / chunksPerSplit;
  const int cL = chunkIdx % chunksPerSplit;
  const int cpr = nXtiles / cc;
  const int m0 = ((cL / cpr) * cr + w / cc) * 128;
  const int n0 = ((cL % cpr) * cc + w % cc) * 128;
  const int kBeg = split * kSplitLen, kEnd = kBeg + kSplitLen;

  const int srow = lane >> 3;
  const int scol = ((lane & 7) ^ srow) * 8;  // pre-swizzled global col (elements)

  f32x4 acc[4][4] = {};

  for (int k0 = kBeg; k0 < kEnd; k0 += 64) {
    if constexpr (A_F32) {
      float4 pa[4][2];
#pragma unroll
      for (int i = 0; i < 4; ++i) {
        const int chunk = i * 4 + wave;
        const int rr = chunk * 8 + srow;
        const float* az = Af + (size_t)(m0 + rr) * K + (k0 + scol);
        pa[i][0] = *(const float4*)az;
        pa[i][1] = *(const float4*)(az + 4);
      }
#pragma unroll
      for (int i = 0; i < 4; ++i) {
        const int chunk = i * 4 + wave;
        short8 cv;
        cv[0] = (short)f2bf(pa[i][0].x); cv[1] = (short)f2bf(pa[i][0].y);
        cv[2] = (short)f2bf(pa[i][0].z); cv[3] = (short)f2bf(pa[i][0].w);
        cv[4] = (short)f2bf(pa[i][1].x); cv[5] = (short)f2bf(pa[i][1].y);
        cv[6] = (short)f2bf(pa[i][1].z); cv[7] = (short)f2bf(pa[i][1].w);
        *(short8*)&sA[chunk * 512 + lane * 8] = cv;
      }
    } else {
#pragma unroll
      for (int i = 0; i < 4; ++i) {
        const int chunk = i * 4 + wave;
        const int rr = chunk * 8 + srow;
        gload_lds16(Ab + (size_t)(m0 + rr) * K + (k0 + scol), &sA[chunk * 512]);
      }
    }
#pragma unroll
    for (int i = 0; i < 4; ++i) {
      const int chunk = i * 4 + wave;
      const int rr = chunk * 8 + srow;
      gload_lds16(Bt + (size_t)(n0 + rr) * K + (k0 + scol), &sB[chunk * 512]);
    }
    __syncthreads();
#pragma unroll
    for (int kk = 0; kk < 64; kk += 32) {
      const int kcol = kk + (lane >> 4) * 8;
      const int kswz = (lane & 7) * 8;
      short8 af[4], bfr[4];
#pragma unroll
      for (int m = 0; m < 4; ++m)
        af[m] = *(const short8*)&sA[(wr * 64 + m * 16 + (lane & 15)) * 64 + (kcol ^ kswz)];
#pragma unroll
      for (int n = 0; n < 4; ++n)
        bfr[n] = *(const short8*)&sB[(wc * 64 + n * 16 + (lane & 15)) * 64 + (kcol ^ kswz)];
#pragma unroll
      for (int m = 0; m < 4; ++m)
#pragma unroll
        for (int n = 0; n < 4; ++n)
          acc[m][n] = __builtin_amdgcn_mfma_f32_16x16x32_bf16(af[m], bfr[n], acc[m][n], 0, 0, 0);
    }
    __syncthreads();
  }

  const int cl = lane & 15, rg = lane >> 4;
  const float* bptr = (split == 0) ? bias : nullptr;
#pragma unroll
  for (int n = 0; n < 4; ++n) {
    const int col = n0 + wc * 64 + n * 16 + cl;
    const float bias_v = bptr ? bptr[col] : 0.0f;
#pragma unroll
    for (int m = 0; m < 4; ++m) {
      const int rbase = m0 + wr * 64 + m * 16 + rg * 4;
#pragma unroll
      for (int j2 = 0; j2 < 4; ++j2) {
        float v = acc[m][n][j2] + bias_v;
        if (ADD_I && (rbase + j2 == col)) v += 1.0f;
        if (RELU) v = fmaxf(v, 0.0f);
        const size_t idx = split * cStride + (size_t)(rbase + j2) * N + col;
        if (OUT_BF16)
          ((unsigned short*)Cout)[idx] = f2bf(v);
        else
          ((float*)Cout)[idx] = v;
      }
    }
  }
}

// -------- LN over D=1024 of sum of 2 bf16 partials -> bf16 out --------
__global__ __launch_bounds__(256) void ln2_bf16_kernel(
    const unsigned short* __restrict__ P, size_t pStr,
    const float* __restrict__ gg, const float* __restrict__ bb,
    unsigned short* __restrict__ Hb) {
  const int row = blockIdx.x, t = threadIdx.x;
  const size_t base = (size_t)row * 1024 + t * 4;
  ushort4 v0 = *(const ushort4*)(P + base);
  ushort4 v1 = *(const ushort4*)(P + pStr + base);
  float a0 = bf2f(v0.x) + bf2f(v1.x);
  float a1 = bf2f(v0.y) + bf2f(v1.y);
  float a2 = bf2f(v0.z) + bf2f(v1.z);
  float a3 = bf2f(v0.w) + bf2f(v1.w);
  float s = a0 + a1 + a2 + a3;
  float ss = a0 * a0 + a1 * a1 + a2 * a2 + a3 * a3;
#pragma unroll
  for (int off = 32; off > 0; off >>= 1) {
    s += __shfl_down(s, off);
    ss += __shfl_down(ss, off);
  }
  __shared__ float rs[4], rss[4];
  __shared__ float smean, srstd;
  const int wave = t >> 6, lane = t & 63;
  if (lane == 0) { rs[wave] = s; rss[wave] = ss; }
  __syncthreads();
  if (t == 0) {
    float S1 = rs[0] + rs[1] + rs[2] + rs[3];
    float S2 = rss[0] + rss[1] + rss[2] + rss[3];
    float mean = S1 * (1.0f / 1024.0f);
    float var = S2 * (1.0f / 1024.0f) - mean * mean;
    smean = mean;
    srstd = rsqrtf(var + 1e-5f);
  }
  __syncthreads();
  const float mean = smean, rstd = srstd;
  float4 gv = *(const float4*)(gg + t * 4);
  float4 bv = *(const float4*)(bb + t * 4);
  ushort4 hb;
  hb.x = f2bf((a0 - mean) * rstd * gv.x + bv.x);
  hb.y = f2bf((a1 - mean) * rstd * gv.y + bv.y);
  hb.z = f2bf((a2 - mean) * rstd * gv.z + bv.z);
  hb.w = f2bf((a3 - mean) * rstd * gv.w + bv.w);
  *(ushort4*)(Hb + base) = hb;
}

// -------- LN of (bf16 residual + sum of 4 bf16 partials) -> fp32 out --------
__global__ __launch_bounds__(256) void ln_fin4_kernel(
    const unsigned short* __restrict__ Res, const unsigned short* __restrict__ P,
    size_t pStr, const float* __restrict__ gg, const float* __restrict__ bb,
    float* __restrict__ out) {
  const int row = blockIdx.x, t = threadIdx.x;
  const size_t base = (size_t)row * 1024 + t * 4;
  ushort4 rv = *(const ushort4*)(Res + base);
  ushort4 v0 = *(const ushort4*)(P + base);
  ushort4 v1 = *(const ushort4*)(P + pStr + base);
  ushort4 v2 = *(const ushort4*)(P + 2 * pStr + base);
  ushort4 v3 = *(const ushort4*)(P + 3 * pStr + base);
  float a0 = bf2f(rv.x) + bf2f(v0.x) + bf2f(v1.x) + bf2f(v2.x) + bf2f(v3.x);
  float a1 = bf2f(rv.y) + bf2f(v0.y) + bf2f(v1.y) + bf2f(v2.y) + bf2f(v3.y);
  float a2 = bf2f(rv.z) + bf2f(v0.z) + bf2f(v1.z) + bf2f(v2.z) + bf2f(v3.z);
  float a3 = bf2f(rv.w) + bf2f(v0.w) + bf2f(v1.w) + bf2f(v2.w) + bf2f(v3.w);
  float s = a0 + a1 + a2 + a3;
  float ss = a0 * a0 + a1 * a1 + a2 * a2 + a3 * a3;
#pragma unroll
  for (int off = 32; off > 0; off >>= 1) {
    s += __shfl_down(s, off);
    ss += __shfl_down(ss, off);
  }
  __shared__ float rs[4], rss[4];
  __shared__ float smean, srstd;
  const int wave = t >> 6, lane = t & 63;
  if (lane == 0) { rs[wave] = s; rss[wave] = ss; }
  __syncthreads();
  if (t == 0) {
    float S1 = rs[0] + rs[1] + rs[2] + rs[3];
    float S2 = rss[0] + rss[1] + rss[2] + rss[3];
    float mean = S1 * (1.0f / 1024.0f);
    float var = S2 * (1.0f / 1024.0f) - mean * mean;
    smean = mean;
    srstd = rsqrtf(var + 1e-5f);
  }
  __syncthreads();
  const float mean = smean, rstd = srstd;
  float4 gv = *(const float4*)(gg + t * 4);
  float4 bv = *(const float4*)(bb + t * 4);
  float4 ov;
  ov.x = (a0 - mean) * rstd * gv.x + bv.x;
  ov.y = (a1 - mean) * rstd * gv.y + bv.y;
  ov.z = (a2 - mean) * rstd * gv.z + bv.z;
  ov.w = (a3 - mean) * rstd * gv.w + bv.w;
  *(float4*)(out + base) = ov;
}

// ---------------------------------------------------------------------------
// Attention is algebraically dead: softmax over q sums to 1 per (b,h,k) column;
// summed over k -> s_bh == S == 2048 exactly. Folding the residual too:
//   h1  = LN( z @ (I + 2048*Wv@Wo) + (2048*bv@Wo + bo) )
//   out = LN( h1 + relu(h1@W1+b1)@W2 + b2 )
// q, k, mask, x, y, Wq, Wk are all unused.
// ---------------------------------------------------------------------------
extern "C" void kernel_launch(void* const* d_in, const int* in_sizes, int n_in,
                              void* d_out, int out_size, void* d_ws, size_t ws_size,
                              hipStream_t stream) {
  const float* z  = (const float*)d_in[2];
  const float* Wv = (const float*)d_in[8];
  const float* bv = (const float*)d_in[9];
  const float* Wo = (const float*)d_in[10];
  const float* bo = (const float*)d_in[11];
  const float* W1 = (const float*)d_in[12];
  const float* b1 = (const float*)d_in[13];
  const float* W2 = (const float*)d_in[14];
  const float* b2 = (const float*)d_in[15];
  const float* lng = (const float*)d_in[16];
  const float* lnb = (const float*)d_in[17];
  float* out = (float*)d_out;

  char* ws = (char*)d_ws;
  // layout (MB offsets), peak 112MB, lifetimes checked:
  //   0..32  : a1 (FF1 out, alive to FF2)
  //   32..64 : attP bf16 2x8MB (dead after LN1) -> ffP bf16 4x8MB (alive to LN2)
  //   64..72 : W2T (written upfront, read at FF2)
  //   88..96 : WoT(88..90) WvBf(90..92) WcT(92..94) bc(94) bprt(94+64K)
  //   96..104: h1bf (LN1 out, alive to LN2)
  //   104..112: W1T
  unsigned short* a1   = (unsigned short*)(ws + 0 * MB);
  unsigned short* attP = (unsigned short*)(ws + 32 * MB);
  unsigned short* ffP  = (unsigned short*)(ws + 32 * MB);
  unsigned short* W2T  = (unsigned short*)(ws + 64 * MB);
  unsigned short* WoT  = (unsigned short*)(ws + 88 * MB);
  unsigned short* WvBf = (unsigned short*)(ws + 90 * MB);
  unsigned short* WcT  = (unsigned short*)(ws + 92 * MB);
  float*          bc   = (float*)(ws + 94 * MB);
  float*          bprt = (float*)(ws + 94 * MB + 65536);
  unsigned short* h1bf = (unsigned short*)(ws + 96 * MB);
  unsigned short* W1T  = (unsigned short*)(ws + 104 * MB);

  const size_t pStr = (size_t)kM * kD;  // elements per partial

  // --- weight prep ---
  cast_transpose64<<<dim3(256), dim3(256), 0, stream>>>(
      Wo, WoT, kD, kD, (float)kS, kD / 64);        // WoT[n][f] = 2048*Wo[f][n]
  cast_bf16_kernel<<<dim3(kD * kD / 1024), dim3(256), 0, stream>>>(Wv, WvBf, kD * kD);
  bias_gemv_part_kernel<<<dim3(128), dim3(256), 0, stream>>>(bv, Wo, bprt);
  bias_gemv_fin_kernel<<<dim3(4), dim3(256), 0, stream>>>(bprt, bo, bc);

  // WcT = I + (2048*Wv@Wo)^T : unsplit grid 64, identity + bf16 fused in epilogue
  gemm_bt<1, 0, 1, 0><<<dim3(64), dim3(256), 0, stream>>>(
      WoT, WvBf, nullptr, WcT, kD, kD, kD, kD / 128, 64, kD, 0, 4, 2);

  // attP = z @ WcT^T + bc : split-K x2 (grid 512), A staged fp32->bf16 in-kernel
  gemm_bt<1, 0, 0, 1><<<dim3(512), dim3(256), 0, stream>>>(
      z, WcT, bc, attP, kM, kD, kD, kD / 128, 256, 512, pStr, 8, 8);

  // h1 = LN(attP0 + attP1) -> bf16
  ln2_bf16_kernel<<<dim3(kM), dim3(256), 0, stream>>>(attP, pStr, lng, lnb, h1bf);

  // FF1: a1 = relu(h1 @ W1 + b1) : grid 1024 (4 blocks/CU), chunk 16x8/XCD
  cast_transpose64<<<dim3(1024), dim3(256), 0, stream>>>(
      W1, W1T, kD, kFF, 1.0f, kFF / 64);
  gemm_bt<1, 1, 0, 0><<<dim3(1024), dim3(256), 0, stream>>>(
      h1bf, W1T, b1, a1, kM, kFF, kD, kFF / 128, 1024, kD, 0, 16, 8);

  // FF2: ffP = a1 @ W2 + b2 : split-K x4 (grid 1024), chunk 16x8/XCD
  cast_transpose64<<<dim3(1024), dim3(256), 0, stream>>>(
      W2, W2T, kFF, kD, 1.0f, kD / 64);
  gemm_bt<1, 0, 0, 0><<<dim3(1024), dim3(256), 0, stream>>>(
      a1, W2T, b2, ffP, kM, kD, kFF, kD / 128, 256, kFF / 4, pStr, 16, 8);

  // out = LN(h1 + ffP0..3)
  ln_fin4_kernel<<<dim3(kM), dim3(256), 0, stream>>>(h1bf, ffP, pStr, lng, lnb, out);
}

// Round 12
// 159.773 us; speedup vs baseline: 1.2193x; 1.0244x over previous
//
#include <hip/hip_runtime.h>

// Problem constants (from reference)
static constexpr int kB = 2, kS = 2048, kD = 1024, kFF = 4096;
static constexpr int kM = kB * kS;  // 4096 token rows
static constexpr size_t MB = 1u << 20;

typedef __attribute__((ext_vector_type(8))) short short8;
typedef __attribute__((ext_vector_type(4))) float f32x4;

__device__ __forceinline__ unsigned short f2bf(float f) {
  union { float f; unsigned int u; } c; c.f = f;
  unsigned int u = c.u;
  unsigned int r = u + 0x7FFFu + ((u >> 16) & 1u);  // RNE
  return (unsigned short)(r >> 16);
}

__device__ __forceinline__ float bf2f(unsigned short b) {
  union { unsigned int u; float f; } c;
  c.u = ((unsigned int)b) << 16;
  return c.f;
}

__device__ __forceinline__ void gload_lds16(const void* g, void* l) {
  __builtin_amdgcn_global_load_lds(
      (const __attribute__((address_space(1))) void*)g,
      (__attribute__((address_space(3))) void*)l, 16, 0, 0);
}

// ---------------- cast fp32 -> bf16 (vectorized) ----------------
__global__ __launch_bounds__(256) void cast_bf16_kernel(
    const float* __restrict__ in, unsigned short* __restrict__ out, int n) {
  int i = (blockIdx.x * 256 + threadIdx.x) * 4;
  if (i >= n) return;
  float4 v = *(const float4*)(in + i);
  ushort4 o;
  o.x = f2bf(v.x); o.y = f2bf(v.y); o.z = f2bf(v.z); o.w = f2bf(v.w);
  *(ushort4*)(out + i) = o;
}

// ------ cast + transpose: W[K][N] fp32 -> Wt[N][K] bf16 (x scale), 64x64 tiles ------
__global__ __launch_bounds__(256) void cast_transpose64(
    const float* __restrict__ W, unsigned short* __restrict__ Wt,
    int K, int N, float scale, int ntN) {
  __shared__ float tile[64][65];
  const int bid = blockIdx.x;
  const int nb = (bid % ntN) * 64, kb = (bid / ntN) * 64;
  const int tx = threadIdx.x & 15, ty = threadIdx.x >> 4;
#pragma unroll
  for (int p = 0; p < 4; ++p) {
    const int r = ty + 16 * p;
    float4 v = *(const float4*)(W + (size_t)(kb + r) * N + nb + tx * 4);
    tile[r][tx * 4 + 0] = v.x;
    tile[r][tx * 4 + 1] = v.y;
    tile[r][tx * 4 + 2] = v.z;
    tile[r][tx * 4 + 3] = v.w;
  }
  __syncthreads();
#pragma unroll
  for (int p = 0; p < 4; ++p) {
    const int n = ty + 16 * p;
    ushort4 o;
    o.x = f2bf(tile[tx * 4 + 0][n] * scale);
    o.y = f2bf(tile[tx * 4 + 1][n] * scale);
    o.z = f2bf(tile[tx * 4 + 2][n] * scale);
    o.w = f2bf(tile[tx * 4 + 3][n] * scale);
    *(ushort4*)(Wt + (size_t)(nb + n) * K + kb + tx * 4) = o;
  }
}

// --------- parallel GEMV phase 1: partial[b][n] = sum_{f in block b} bv[f]*Wo[f][n] ---
__global__ __launch_bounds__(256) void bias_gemv_part_kernel(
    const float* __restrict__ bv, const float* __restrict__ Wo,
    float* __restrict__ partial) {
  const int b = blockIdx.x, t = threadIdx.x;
  const int c = t * 4;
  float4 acc = {0.f, 0.f, 0.f, 0.f};
#pragma unroll
  for (int r = 0; r < 8; ++r) {
    const int f = b * 8 + r;
    const float s = bv[f];
    float4 w = *(const float4*)(Wo + (size_t)f * 1024 + c);
    acc.x = fmaf(s, w.x, acc.x);
    acc.y = fmaf(s, w.y, acc.y);
    acc.z = fmaf(s, w.z, acc.z);
    acc.w = fmaf(s, w.w, acc.w);
  }
  *(float4*)(partial + (size_t)b * 1024 + c) = acc;
}

// --------- GEMV phase 2: bc[n] = 2048 * sum_b partial[b][n] + bo[n] ---------
__global__ __launch_bounds__(256) void bias_gemv_fin_kernel(
    const float* __restrict__ partial, const float* __restrict__ bo,
    float* __restrict__ bc) {
  const int n = blockIdx.x * 256 + threadIdx.x;
  float acc = 0.0f;
#pragma unroll 8
  for (int b = 0; b < 128; ++b) acc += partial[(size_t)b * 1024 + n];
  bc[n] = 2048.0f * acc + bo[n];
}

// -------- combine 4 bf16 split-K partials of Wc, add identity, cast bf16 --------
__global__ __launch_bounds__(256) void combine_wc4_kernel(
    const unsigned short* __restrict__ P, unsigned short* __restrict__ Wt) {
  const int i = (blockIdx.x * 256 + threadIdx.x) * 4;  // grid 1024
  const int MN = 1024 * 1024;
  ushort4 s0 = *(const ushort4*)(P + i);
  ushort4 s1 = *(const ushort4*)(P + MN + i);
  ushort4 s2 = *(const ushort4*)(P + 2 * MN + i);
  ushort4 s3 = *(const ushort4*)(P + 3 * MN + i);
  const int row = i >> 10, col = i & 1023;
  float v0 = bf2f(s0.x) + bf2f(s1.x) + bf2f(s2.x) + bf2f(s3.x) + (row == col + 0 ? 1.0f : 0.0f);
  float v1 = bf2f(s0.y) + bf2f(s1.y) + bf2f(s2.y) + bf2f(s3.y) + (row == col + 1 ? 1.0f : 0.0f);
  float v2 = bf2f(s0.z) + bf2f(s1.z) + bf2f(s2.z) + bf2f(s3.z) + (row == col + 2 ? 1.0f : 0.0f);
  float v3 = bf2f(s0.w) + bf2f(s1.w) + bf2f(s2.w) + bf2f(s3.w) + (row == col + 3 ? 1.0f : 0.0f);
  ushort4 o; o.x = f2bf(v0); o.y = f2bf(v1); o.z = f2bf(v2); o.w = f2bf(v3);
  *(ushort4*)(Wt + i) = o;
}

// ---------------- GEMM: C[M,N] = A[M,K] @ Bt[N,K]^T (+bias, relu, split-K) ----
// 128x128 tile, BK=64, 4 waves (2x2). Single 32KB LDS buffer (m97 structure;
// latency hiding from 4 blocks/CU TLP). T2 XOR-swizzle: measured 0 conflicts.
// XCD super-chunk mapping (r10). A_F32: stage A fp32->reg->cvt->ds_write
// (fuses the z cast). Requires (nwg/8) % (cr*cc) == 0; bijective.
template <int OUT_BF16, int RELU, int A_F32>
__global__ __launch_bounds__(256, 4) void gemm_bt(
    const void* __restrict__ A, const unsigned short* __restrict__ Bt,
    const float* __restrict__ bias, void* __restrict__ Cout,
    int M, int N, int K, int nXtiles, int nTilesPerSplit, int kSplitLen,
    size_t cStride, int cr, int cc) {
  __shared__ __align__(16) unsigned short sA[128 * 64];
  __shared__ __align__(16) unsigned short sB[128 * 64];
  const unsigned short* Ab = (const unsigned short*)A;
  const float* Af = (const float*)A;
  const int tid = threadIdx.x;
  const int wave = tid >> 6, lane = tid & 63;
  const int wr = wave >> 1, wc = wave & 1;

  // super-chunk XCD decomposition
  const int x = blockIdx.x & 7, j = blockIdx.x >> 3;
  const int bpc = cr * cc;
  const int chunkIdx = x + 8 * (j / bpc);
  const int w = j % bpc;
  const int chunksPerSplit = nTilesPerSplit / bpc;
  const int split = chunkIdx / chunksPerSplit;
  const int cL = chunkIdx % chunksPerSplit;
  const int cpr = nXtiles / cc;
  const int m0 = ((cL / cpr) * cr + w / cc) * 128;
  const int n0 = ((cL % cpr) * cc + w % cc) * 128;
  const int kBeg = split * kSplitLen, kEnd = kBeg + kSplitLen;

  const int srow = lane >> 3;
  const int scol = ((lane & 7) ^ srow) * 8;  // pre-swizzled global col (elements)

  f32x4 acc[4][4] = {};

  for (int k0 = kBeg; k0 < kEnd; k0 += 64) {
    if constexpr (A_F32) {
      float4 pa[4][2];
#pragma unroll
      for (int i = 0; i < 4; ++i) {
        const int chunk = i * 4 + wave;
        const int rr = chunk * 8 + srow;
        const float* az = Af + (size_t)(m0 + rr) * K + (k0 + scol);
        pa[i][0] = *(const float4*)az;
        pa[i][1] = *(const float4*)(az + 4);
      }
#pragma unroll
      for (int i = 0; i < 4; ++i) {
        const int chunk = i * 4 + wave;
        short8 cv;
        cv[0] = (short)f2bf(pa[i][0].x); cv[1] = (short)f2bf(pa[i][0].y);
        cv[2] = (short)f2bf(pa[i][0].z); cv[3] = (short)f2bf(pa[i][0].w);
        cv[4] = (short)f2bf(pa[i][1].x); cv[5] = (short)f2bf(pa[i][1].y);
        cv[6] = (short)f2bf(pa[i][1].z); cv[7] = (short)f2bf(pa[i][1].w);
        *(short8*)&sA[chunk * 512 + lane * 8] = cv;
      }
    } else {
#pragma unroll
      for (int i = 0; i < 4; ++i) {
        const int chunk = i * 4 + wave;
        const int rr = chunk * 8 + srow;
        gload_lds16(Ab + (size_t)(m0 + rr) * K + (k0 + scol), &sA[chunk * 512]);
      }
    }
#pragma unroll
    for (int i = 0; i < 4; ++i) {
      const int chunk = i * 4 + wave;
      const int rr = chunk * 8 + srow;
      gload_lds16(Bt + (size_t)(n0 + rr) * K + (k0 + scol), &sB[chunk * 512]);
    }
    __syncthreads();
#pragma unroll
    for (int kk = 0; kk < 64; kk += 32) {
      const int kcol = kk + (lane >> 4) * 8;
      const int kswz = (lane & 7) * 8;
      short8 af[4], bfr[4];
#pragma unroll
      for (int m = 0; m < 4; ++m)
        af[m] = *(const short8*)&sA[(wr * 64 + m * 16 + (lane & 15)) * 64 + (kcol ^ kswz)];
#pragma unroll
      for (int n = 0; n < 4; ++n)
        bfr[n] = *(const short8*)&sB[(wc * 64 + n * 16 + (lane & 15)) * 64 + (kcol ^ kswz)];
#pragma unroll
      for (int m = 0; m < 4; ++m)
#pragma unroll
        for (int n = 0; n < 4; ++n)
          acc[m][n] = __builtin_amdgcn_mfma_f32_16x16x32_bf16(af[m], bfr[n], acc[m][n], 0, 0, 0);
    }
    __syncthreads();
  }

  const int cl = lane & 15, rg = lane >> 4;
  const float* bptr = (split == 0) ? bias : nullptr;
#pragma unroll
  for (int n = 0; n < 4; ++n) {
    const int col = n0 + wc * 64 + n * 16 + cl;
    const float bias_v = bptr ? bptr[col] : 0.0f;
#pragma unroll
    for (int m = 0; m < 4; ++m) {
      const int rbase = m0 + wr * 64 + m * 16 + rg * 4;
#pragma unroll
      for (int j2 = 0; j2 < 4; ++j2) {
        float v = acc[m][n][j2] + bias_v;
        if (RELU) v = fmaxf(v, 0.0f);
        const size_t idx = split * cStride + (size_t)(rbase + j2) * N + col;
        if (OUT_BF16)
          ((unsigned short*)Cout)[idx] = f2bf(v);
        else
          ((float*)Cout)[idx] = v;
      }
    }
  }
}

// -------- LN over D=1024 of sum of 4 bf16 partials -> bf16 out --------
__global__ __launch_bounds__(256) void ln4_bf16_kernel(
    const unsigned short* __restrict__ P, size_t pStr,
    const float* __restrict__ gg, const float* __restrict__ bb,
    unsigned short* __restrict__ Hb) {
  const int row = blockIdx.x, t = threadIdx.x;
  const size_t base = (size_t)row * 1024 + t * 4;
  ushort4 v0 = *(const ushort4*)(P + base);
  ushort4 v1 = *(const ushort4*)(P + pStr + base);
  ushort4 v2 = *(const ushort4*)(P + 2 * pStr + base);
  ushort4 v3 = *(const ushort4*)(P + 3 * pStr + base);
  float a0 = bf2f(v0.x) + bf2f(v1.x) + bf2f(v2.x) + bf2f(v3.x);
  float a1 = bf2f(v0.y) + bf2f(v1.y) + bf2f(v2.y) + bf2f(v3.y);
  float a2 = bf2f(v0.z) + bf2f(v1.z) + bf2f(v2.z) + bf2f(v3.z);
  float a3 = bf2f(v0.w) + bf2f(v1.w) + bf2f(v2.w) + bf2f(v3.w);
  float s = a0 + a1 + a2 + a3;
  float ss = a0 * a0 + a1 * a1 + a2 * a2 + a3 * a3;
#pragma unroll
  for (int off = 32; off > 0; off >>= 1) {
    s += __shfl_down(s, off);
    ss += __shfl_down(ss, off);
  }
  __shared__ float rs[4], rss[4];
  __shared__ float smean, srstd;
  const int wave = t >> 6, lane = t & 63;
  if (lane == 0) { rs[wave] = s; rss[wave] = ss; }
  __syncthreads();
  if (t == 0) {
    float S1 = rs[0] + rs[1] + rs[2] + rs[3];
    float S2 = rss[0] + rss[1] + rss[2] + rss[3];
    float mean = S1 * (1.0f / 1024.0f);
    float var = S2 * (1.0f / 1024.0f) - mean * mean;
    smean = mean;
    srstd = rsqrtf(var + 1e-5f);
  }
  __syncthreads();
  const float mean = smean, rstd = srstd;
  float4 gv = *(const float4*)(gg + t * 4);
  float4 bv = *(const float4*)(bb + t * 4);
  ushort4 hb;
  hb.x = f2bf((a0 - mean) * rstd * gv.x + bv.x);
  hb.y = f2bf((a1 - mean) * rstd * gv.y + bv.y);
  hb.z = f2bf((a2 - mean) * rstd * gv.z + bv.z);
  hb.w = f2bf((a3 - mean) * rstd * gv.w + bv.w);
  *(ushort4*)(Hb + base) = hb;
}

// -------- LN of (bf16 residual + sum of 4 bf16 partials) -> fp32 out --------
__global__ __launch_bounds__(256) void ln_fin4_kernel(
    const unsigned short* __restrict__ Res, const unsigned short* __restrict__ P,
    size_t pStr, const float* __restrict__ gg, const float* __restrict__ bb,
    float* __restrict__ out) {
  const int row = blockIdx.x, t = threadIdx.x;
  const size_t base = (size_t)row * 1024 + t * 4;
  ushort4 rv = *(const ushort4*)(Res + base);
  ushort4 v0 = *(const ushort4*)(P + base);
  ushort4 v1 = *(const ushort4*)(P + pStr + base);
  ushort4 v2 = *(const ushort4*)(P + 2 * pStr + base);
  ushort4 v3 = *(const ushort4*)(P + 3 * pStr + base);
  float a0 = bf2f(rv.x) + bf2f(v0.x) + bf2f(v1.x) + bf2f(v2.x) + bf2f(v3.x);
  float a1 = bf2f(rv.y) + bf2f(v0.y) + bf2f(v1.y) + bf2f(v2.y) + bf2f(v3.y);
  float a2 = bf2f(rv.z) + bf2f(v0.z) + bf2f(v1.z) + bf2f(v2.z) + bf2f(v3.z);
  float a3 = bf2f(rv.w) + bf2f(v0.w) + bf2f(v1.w) + bf2f(v2.w) + bf2f(v3.w);
  float s = a0 + a1 + a2 + a3;
  float ss = a0 * a0 + a1 * a1 + a2 * a2 + a3 * a3;
#pragma unroll
  for (int off = 32; off > 0; off >>= 1) {
    s += __shfl_down(s, off);
    ss += __shfl_down(ss, off);
  }
  __shared__ float rs[4], rss[4];
  __shared__ float smean, srstd;
  const int wave = t >> 6, lane = t & 63;
  if (lane == 0) { rs[wave] = s; rss[wave] = ss; }
  __syncthreads();
  if (t == 0) {
    float S1 = rs[0] + rs[1] + rs[2] + rs[3];
    float S2 = rss[0] + rss[1] + rss[2] + rss[3];
    float mean = S1 * (1.0f / 1024.0f);
    float var = S2 * (1.0f / 1024.0f) - mean * mean;
    smean = mean;
    srstd = rsqrtf(var + 1e-5f);
  }
  __syncthreads();
  const float mean = smean, rstd = srstd;
  float4 gv = *(const float4*)(gg + t * 4);
  float4 bv = *(const float4*)(bb + t * 4);
  float4 ov;
  ov.x = (a0 - mean) * rstd * gv.x + bv.x;
  ov.y = (a1 - mean) * rstd * gv.y + bv.y;
  ov.z = (a2 - mean) * rstd * gv.z + bv.z;
  ov.w = (a3 - mean) * rstd * gv.w + bv.w;
  *(float4*)(out + base) = ov;
}

// ---------------------------------------------------------------------------
// Attention is algebraically dead: softmax over q sums to 1 per (b,h,k) column;
// summed over k -> s_bh == S == 2048 exactly. Folding the residual too:
//   h1  = LN( z @ (I + 2048*Wv@Wo) + (2048*bv@Wo + bo) )
//   out = LN( h1 + relu(h1@W1+b1)@W2 + b2 )
// q, k, mask, x, y, Wq, Wk are all unused.
// ---------------------------------------------------------------------------
extern "C" void kernel_launch(void* const* d_in, const int* in_sizes, int n_in,
                              void* d_out, int out_size, void* d_ws, size_t ws_size,
                              hipStream_t stream) {
  const float* z  = (const float*)d_in[2];
  const float* Wv = (const float*)d_in[8];
  const float* bv = (const float*)d_in[9];
  const float* Wo = (const float*)d_in[10];
  const float* bo = (const float*)d_in[11];
  const float* W1 = (const float*)d_in[12];
  const float* b1 = (const float*)d_in[13];
  const float* W2 = (const float*)d_in[14];
  const float* b2 = (const float*)d_in[15];
  const float* lng = (const float*)d_in[16];
  const float* lnb = (const float*)d_in[17];
  float* out = (float*)d_out;

  char* ws = (char*)d_ws;
  // layout (MB offsets), peak 112MB, lifetimes checked:
  //   0..32  : a1 (FF1 out, alive to FF2)
  //   32..64 : attP bf16 4x8MB (dead after LN1) -> ffP bf16 4x8MB (alive to LN2)
  //   64..72 : wcpB bf16 4x2MB (dead after combine) -> W2T (written just
  //            before FF2, long after combine)
  //   88..96 : WoT(88..90) WvBf(90..92) WcT(92..94) bc(94) bprt(94+64K)
  //   96..104: h1bf (LN1 out, alive to LN2)
  //   104..112: W1T
  unsigned short* a1   = (unsigned short*)(ws + 0 * MB);
  unsigned short* attP = (unsigned short*)(ws + 32 * MB);
  unsigned short* ffP  = (unsigned short*)(ws + 32 * MB);
  unsigned short* wcpB = (unsigned short*)(ws + 64 * MB);
  unsigned short* W2T  = (unsigned short*)(ws + 64 * MB);
  unsigned short* WoT  = (unsigned short*)(ws + 88 * MB);
  unsigned short* WvBf = (unsigned short*)(ws + 90 * MB);
  unsigned short* WcT  = (unsigned short*)(ws + 92 * MB);
  float*          bc   = (float*)(ws + 94 * MB);
  float*          bprt = (float*)(ws + 94 * MB + 65536);
  unsigned short* h1bf = (unsigned short*)(ws + 96 * MB);
  unsigned short* W1T  = (unsigned short*)(ws + 104 * MB);

  const size_t pStr = (size_t)kM * kD;     // elements per activation partial
  const size_t wStr = (size_t)kD * kD;     // elements per Wc partial

  // --- weight prep ---
  cast_transpose64<<<dim3(256), dim3(256), 0, stream>>>(
      Wo, WoT, kD, kD, (float)kS, kD / 64);        // WoT[n][f] = 2048*Wo[f][n]
  cast_bf16_kernel<<<dim3(kD * kD / 1024), dim3(256), 0, stream>>>(Wv, WvBf, kD * kD);
  bias_gemv_part_kernel<<<dim3(128), dim3(256), 0, stream>>>(bv, Wo, bprt);
  bias_gemv_fin_kernel<<<dim3(4), dim3(256), 0, stream>>>(bprt, bo, bc);

  // Wc partials = (2048*Wv@Wo)^T : split-K x4 (grid 256, 1 block/CU, K=4 steps)
  gemm_bt<1, 0, 0><<<dim3(256), dim3(256), 0, stream>>>(
      WoT, WvBf, nullptr, wcpB, kD, kD, kD, kD / 128, 64, 256, wStr, 8, 4);
  // WcT = sum of partials + I, bf16
  combine_wc4_kernel<<<dim3(1024), dim3(256), 0, stream>>>(wcpB, WcT);

  // attP = z @ WcT^T + bc : split-K x4 (grid 1024, 4 blocks/CU, K=4 steps),
  // A staged fp32->bf16 in-kernel
  gemm_bt<1, 0, 1><<<dim3(1024), dim3(256), 0, stream>>>(
      z, WcT, bc, attP, kM, kD, kD, kD / 128, 256, 256, pStr, 8, 8);

  // h1 = LN(attP0..3) -> bf16
  ln4_bf16_kernel<<<dim3(kM), dim3(256), 0, stream>>>(attP, pStr, lng, lnb, h1bf);

  // FF1: a1 = relu(h1 @ W1 + b1) : grid 1024 (4 blocks/CU), chunk 16x8/XCD
  cast_transpose64<<<dim3(1024), dim3(256), 0, stream>>>(
      W1, W1T, kD, kFF, 1.0f, kFF / 64);
  gemm_bt<1, 1, 0><<<dim3(1024), dim3(256), 0, stream>>>(
      h1bf, W1T, b1, a1, kM, kFF, kD, kFF / 128, 1024, kD, 0, 16, 8);

  // FF2: ffP = a1 @ W2 + b2 : split-K x4 (grid 1024), chunk 16x8/XCD
  cast_transpose64<<<dim3(1024), dim3(256), 0, stream>>>(
      W2, W2T, kFF, kD, 1.0f, kD / 64);
  gemm_bt<1, 0, 0><<<dim3(1024), dim3(256), 0, stream>>>(
      a1, W2T, b2, ffP, kM, kD, kFF, kD / 128, 256, kFF / 4, pStr, 16, 8);

  // out = LN(h1 + ffP0..3)
  ln_fin4_kernel<<<dim3(kM), dim3(256), 0, stream>>>(h1bf, ffP, pStr, lng, lnb, out);
}

// Round 13
// 144.694 us; speedup vs baseline: 1.3464x; 1.1042x over previous
//
#include <hip/hip_runtime.h>

// Problem constants (from reference)
static constexpr int kB = 2, kS = 2048, kD = 1024, kFF = 4096;
static constexpr int kM = kB * kS;  // 4096 token rows
static constexpr size_t MB = 1u << 20;

typedef __attribute__((ext_vector_type(8))) short short8;
typedef __attribute__((ext_vector_type(8))) unsigned short ushort8;
typedef __attribute__((ext_vector_type(4))) float f32x4;

__device__ __forceinline__ unsigned short f2bf(float f) {
  union { float f; unsigned int u; } c; c.f = f;
  unsigned int u = c.u;
  unsigned int r = u + 0x7FFFu + ((u >> 16) & 1u);  // RNE
  return (unsigned short)(r >> 16);
}

__device__ __forceinline__ float bf2f(unsigned short b) {
  union { unsigned int u; float f; } c;
  c.u = ((unsigned int)b) << 16;
  return c.f;
}

__device__ __forceinline__ void gload_lds16(const void* g, void* l) {
  __builtin_amdgcn_global_load_lds(
      (const __attribute__((address_space(1))) void*)g,
      (__attribute__((address_space(3))) void*)l, 16, 0, 0);
}

// ------ cast+transpose 64x64 tile helper (used inside merged prep kernel) ------
__device__ __forceinline__ void do_ct64(
    const float* __restrict__ W, unsigned short* __restrict__ Wt,
    int K, int N, float scale, int ntN, int b, float (*tile)[65]) {
  const int nb = (b % ntN) * 64, kb = (b / ntN) * 64;
  const int tx = threadIdx.x & 15, ty = threadIdx.x >> 4;
#pragma unroll
  for (int p = 0; p < 4; ++p) {
    const int r = ty + 16 * p;
    float4 v = *(const float4*)(W + (size_t)(kb + r) * N + nb + tx * 4);
    tile[r][tx * 4 + 0] = v.x;
    tile[r][tx * 4 + 1] = v.y;
    tile[r][tx * 4 + 2] = v.z;
    tile[r][tx * 4 + 3] = v.w;
  }
  __syncthreads();
#pragma unroll
  for (int p = 0; p < 4; ++p) {
    const int n = ty + 16 * p;
    ushort4 o;
    o.x = f2bf(tile[tx * 4 + 0][n] * scale);
    o.y = f2bf(tile[tx * 4 + 1][n] * scale);
    o.z = f2bf(tile[tx * 4 + 2][n] * scale);
    o.w = f2bf(tile[tx * 4 + 3][n] * scale);
    *(ushort4*)(Wt + (size_t)(nb + n) * K + kb + tx * 4) = o;
  }
}

// ---- merged weight prep: Wo^T(x2048), W1^T, W2^T, cast(Wv), bias-GEMV part ----
// grid 3456 x 256:
//   [0,256)      ct64 Wo  (1024x1024, ntN=16) scale 2048 -> WoT
//   [256,1280)   ct64 W1  (1024x4096, ntN=64) -> W1T
//   [1280,2304)  ct64 W2  (4096x1024, ntN=16) -> W2T
//   [2304,3328)  cast Wv -> WvBf
//   [3328,3456)  bias_gemv_part -> bprt
__global__ __launch_bounds__(256) void prep_kernel(
    const float* __restrict__ Wo, const float* __restrict__ Wv,
    const float* __restrict__ W1, const float* __restrict__ W2,
    const float* __restrict__ bv,
    unsigned short* __restrict__ WoT, unsigned short* __restrict__ WvBf,
    unsigned short* __restrict__ W1T, unsigned short* __restrict__ W2T,
    float* __restrict__ bprt) {
  __shared__ float tile[64][65];
  const int b = blockIdx.x;
  if (b < 256) {
    do_ct64(Wo, WoT, kD, kD, (float)kS, 16, b, tile);
  } else if (b < 1280) {
    do_ct64(W1, W1T, kD, kFF, 1.0f, 64, b - 256, tile);
  } else if (b < 2304) {
    do_ct64(W2, W2T, kFF, kD, 1.0f, 16, b - 1280, tile);
  } else if (b < 3328) {
    const int i = ((b - 2304) * 256 + threadIdx.x) * 4;
    float4 v = *(const float4*)(Wv + i);
    ushort4 o;
    o.x = f2bf(v.x); o.y = f2bf(v.y); o.z = f2bf(v.z); o.w = f2bf(v.w);
    *(ushort4*)(WvBf + i) = o;
  } else {
    const int bb = b - 3328, t = threadIdx.x;
    const int c = t * 4;
    float4 acc = {0.f, 0.f, 0.f, 0.f};
#pragma unroll
    for (int r = 0; r < 8; ++r) {
      const int f = bb * 8 + r;
      const float s = bv[f];
      float4 w = *(const float4*)(Wo + (size_t)f * 1024 + c);
      acc.x = fmaf(s, w.x, acc.x);
      acc.y = fmaf(s, w.y, acc.y);
      acc.z = fmaf(s, w.z, acc.z);
      acc.w = fmaf(s, w.w, acc.w);
    }
    *(float4*)(bprt + (size_t)bb * 1024 + c) = acc;
  }
}

// -------- combine 4 bf16 Wc partials + I -> WcT bf16; blocks 0-3 also finish bc ----
__global__ __launch_bounds__(256) void combine_wc4_fin_kernel(
    const unsigned short* __restrict__ P, unsigned short* __restrict__ Wt,
    const float* __restrict__ bprt, const float* __restrict__ bo,
    float* __restrict__ bc) {
  const int i = (blockIdx.x * 256 + threadIdx.x) * 4;  // grid 1024
  const int MN = 1024 * 1024;
  ushort4 s0 = *(const ushort4*)(P + i);
  ushort4 s1 = *(const ushort4*)(P + MN + i);
  ushort4 s2 = *(const ushort4*)(P + 2 * MN + i);
  ushort4 s3 = *(const ushort4*)(P + 3 * MN + i);
  const int row = i >> 10, col = i & 1023;
  float v0 = bf2f(s0.x) + bf2f(s1.x) + bf2f(s2.x) + bf2f(s3.x) + (row == col + 0 ? 1.0f : 0.0f);
  float v1 = bf2f(s0.y) + bf2f(s1.y) + bf2f(s2.y) + bf2f(s3.y) + (row == col + 1 ? 1.0f : 0.0f);
  float v2 = bf2f(s0.z) + bf2f(s1.z) + bf2f(s2.z) + bf2f(s3.z) + (row == col + 2 ? 1.0f : 0.0f);
  float v3 = bf2f(s0.w) + bf2f(s1.w) + bf2f(s2.w) + bf2f(s3.w) + (row == col + 3 ? 1.0f : 0.0f);
  ushort4 o; o.x = f2bf(v0); o.y = f2bf(v1); o.z = f2bf(v2); o.w = f2bf(v3);
  *(ushort4*)(Wt + i) = o;
  if (blockIdx.x < 4) {
    const int n = blockIdx.x * 256 + threadIdx.x;
    float acc = 0.0f;
#pragma unroll 8
    for (int bb = 0; bb < 128; ++bb) acc += bprt[(size_t)bb * 1024 + n];
    bc[n] = 2048.0f * acc + bo[n];
  }
}

// ---------------- GEMM: C[M,N] = A[M,K] @ Bt[N,K]^T (+bias, relu, split-K) ----
// 128x128 tile, BK=64, 4 waves (2x2). Single 32KB LDS buffer (m97 structure;
// 4 blocks/CU TLP -- the hard cap: 60 VGPR + 64 acc-AGPR ~ 124 regs/wave).
// T2 XOR-swizzle (0 conflicts measured). XCD super-chunk mapping (r10).
// A_F32: stage A fp32->reg->cvt->ds_write (fuses the z cast).
template <int OUT_BF16, int RELU, int A_F32>
__global__ __launch_bounds__(256, 4) void gemm_bt(
    const void* __restrict__ A, const unsigned short* __restrict__ Bt,
    const float* __restrict__ bias, void* __restrict__ Cout,
    int M, int N, int K, int nXtiles, int nTilesPerSplit, int kSplitLen,
    size_t cStride, int cr, int cc) {
  __shared__ __align__(16) unsigned short sA[128 * 64];
  __shared__ __align__(16) unsigned short sB[128 * 64];
  const unsigned short* Ab = (const unsigned short*)A;
  const float* Af = (const float*)A;
  const int tid = threadIdx.x;
  const int wave = tid >> 6, lane = tid & 63;
  const int wr = wave >> 1, wc = wave & 1;

  // super-chunk XCD decomposition (bijective; (nwg/8) % (cr*cc) == 0)
  const int x = blockIdx.x & 7, j = blockIdx.x >> 3;
  const int bpc = cr * cc;
  const int chunkIdx = x + 8 * (j / bpc);
  const int w = j % bpc;
  const int chunksPerSplit = nTilesPerSplit / bpc;
  const int split = chunkIdx / chunksPerSplit;
  const int cL = chunkIdx % chunksPerSplit;
  const int cpr = nXtiles / cc;
  const int m0 = ((cL / cpr) * cr + w / cc) * 128;
  const int n0 = ((cL % cpr) * cc + w % cc) * 128;
  const int kBeg = split * kSplitLen, kEnd = kBeg + kSplitLen;

  const int srow = lane >> 3;
  const int scol = ((lane & 7) ^ srow) * 8;  // pre-swizzled global col (elements)

  f32x4 acc[4][4] = {};

  for (int k0 = kBeg; k0 < kEnd; k0 += 64) {
    if constexpr (A_F32) {
      float4 pa[4][2];
#pragma unroll
      for (int i = 0; i < 4; ++i) {
        const int chunk = i * 4 + wave;
        const int rr = chunk * 8 + srow;
        const float* az = Af + (size_t)(m0 + rr) * K + (k0 + scol);
        pa[i][0] = *(const float4*)az;
        pa[i][1] = *(const float4*)(az + 4);
      }
#pragma unroll
      for (int i = 0; i < 4; ++i) {
        const int chunk = i * 4 + wave;
        short8 cv;
        cv[0] = (short)f2bf(pa[i][0].x); cv[1] = (short)f2bf(pa[i][0].y);
        cv[2] = (short)f2bf(pa[i][0].z); cv[3] = (short)f2bf(pa[i][0].w);
        cv[4] = (short)f2bf(pa[i][1].x); cv[5] = (short)f2bf(pa[i][1].y);
        cv[6] = (short)f2bf(pa[i][1].z); cv[7] = (short)f2bf(pa[i][1].w);
        *(short8*)&sA[chunk * 512 + lane * 8] = cv;
      }
    } else {
#pragma unroll
      for (int i = 0; i < 4; ++i) {
        const int chunk = i * 4 + wave;
        const int rr = chunk * 8 + srow;
        gload_lds16(Ab + (size_t)(m0 + rr) * K + (k0 + scol), &sA[chunk * 512]);
      }
    }
#pragma unroll
    for (int i = 0; i < 4; ++i) {
      const int chunk = i * 4 + wave;
      const int rr = chunk * 8 + srow;
      gload_lds16(Bt + (size_t)(n0 + rr) * K + (k0 + scol), &sB[chunk * 512]);
    }
    __syncthreads();
#pragma unroll
    for (int kk = 0; kk < 64; kk += 32) {
      const int kcol = kk + (lane >> 4) * 8;
      const int kswz = (lane & 7) * 8;
      short8 af[4], bfr[4];
#pragma unroll
      for (int m = 0; m < 4; ++m)
        af[m] = *(const short8*)&sA[(wr * 64 + m * 16 + (lane & 15)) * 64 + (kcol ^ kswz)];
#pragma unroll
      for (int n = 0; n < 4; ++n)
        bfr[n] = *(const short8*)&sB[(wc * 64 + n * 16 + (lane & 15)) * 64 + (kcol ^ kswz)];
#pragma unroll
      for (int m = 0; m < 4; ++m)
#pragma unroll
        for (int n = 0; n < 4; ++n)
          acc[m][n] = __builtin_amdgcn_mfma_f32_16x16x32_bf16(af[m], bfr[n], acc[m][n], 0, 0, 0);
    }
    __syncthreads();
  }

  const int cl = lane & 15, rg = lane >> 4;
  const float* bptr = (split == 0) ? bias : nullptr;
#pragma unroll
  for (int n = 0; n < 4; ++n) {
    const int col = n0 + wc * 64 + n * 16 + cl;
    const float bias_v = bptr ? bptr[col] : 0.0f;
#pragma unroll
    for (int m = 0; m < 4; ++m) {
      const int rbase = m0 + wr * 64 + m * 16 + rg * 4;
#pragma unroll
      for (int j2 = 0; j2 < 4; ++j2) {
        float v = acc[m][n][j2] + bias_v;
        if (RELU) v = fmaxf(v, 0.0f);
        const size_t idx = split * cStride + (size_t)(rbase + j2) * N + col;
        if (OUT_BF16)
          ((unsigned short*)Cout)[idx] = f2bf(v);
        else
          ((float*)Cout)[idx] = v;
      }
    }
  }
}

// -------- LN (wave-per-row): h1 = LN(sum of 4 bf16 partials) -> bf16 --------
// grid kM/4, 256 thr = 4 waves = 4 rows; pure shuffle reduce, no LDS/barriers.
__global__ __launch_bounds__(256) void ln4_wave_kernel(
    const unsigned short* __restrict__ P, size_t pStr,
    const float* __restrict__ gg, const float* __restrict__ bb,
    unsigned short* __restrict__ Hb) {
  const int wave = threadIdx.x >> 6, lane = threadIdx.x & 63;
  const int row = blockIdx.x * 4 + wave;
  const size_t rbase = (size_t)row * 1024;
  float a[16];
#pragma unroll
  for (int sw = 0; sw < 2; ++sw) {
    const size_t idx = rbase + sw * 512 + lane * 8;
    ushort8 v0 = *(const ushort8*)(P + idx);
    ushort8 v1 = *(const ushort8*)(P + pStr + idx);
    ushort8 v2 = *(const ushort8*)(P + 2 * pStr + idx);
    ushort8 v3 = *(const ushort8*)(P + 3 * pStr + idx);
#pragma unroll
    for (int j = 0; j < 8; ++j)
      a[sw * 8 + j] = bf2f(v0[j]) + bf2f(v1[j]) + bf2f(v2[j]) + bf2f(v3[j]);
  }
  float s = 0.f, ss = 0.f;
#pragma unroll
  for (int j = 0; j < 16; ++j) { s += a[j]; ss += a[j] * a[j]; }
#pragma unroll
  for (int off = 32; off > 0; off >>= 1) {
    s += __shfl_down(s, off);
    ss += __shfl_down(ss, off);
  }
  s = __shfl(s, 0);
  ss = __shfl(ss, 0);
  const float mean = s * (1.0f / 1024.0f);
  const float rstd = rsqrtf(ss * (1.0f / 1024.0f) - mean * mean + 1e-5f);
#pragma unroll
  for (int sw = 0; sw < 2; ++sw) {
    const int cbase = sw * 512 + lane * 8;
    float4 g0 = *(const float4*)(gg + cbase);
    float4 g1 = *(const float4*)(gg + cbase + 4);
    float4 b0 = *(const float4*)(bb + cbase);
    float4 b1 = *(const float4*)(bb + cbase + 4);
    const float* gp0 = &g0.x; const float* gp1 = &g1.x;
    const float* bp0 = &b0.x; const float* bp1 = &b1.x;
    ushort8 o;
#pragma unroll
    for (int j = 0; j < 4; ++j) {
      o[j]     = f2bf((a[sw * 8 + j]     - mean) * rstd * gp0[j] + bp0[j]);
      o[4 + j] = f2bf((a[sw * 8 + 4 + j] - mean) * rstd * gp1[j] + bp1[j]);
    }
    *(ushort8*)(Hb + rbase + cbase) = o;
  }
}

// -------- LN (wave-per-row): out = LN(h1 + sum of 4 bf16 partials) -> fp32 --------
__global__ __launch_bounds__(256) void ln_fin_wave_kernel(
    const unsigned short* __restrict__ Res, const unsigned short* __restrict__ P,
    size_t pStr, const float* __restrict__ gg, const float* __restrict__ bb,
    float* __restrict__ out) {
  const int wave = threadIdx.x >> 6, lane = threadIdx.x & 63;
  const int row = blockIdx.x * 4 + wave;
  const size_t rbase = (size_t)row * 1024;
  float a[16];
#pragma unroll
  for (int sw = 0; sw < 2; ++sw) {
    const size_t idx = rbase + sw * 512 + lane * 8;
    ushort8 rv = *(const ushort8*)(Res + idx);
    ushort8 v0 = *(const ushort8*)(P + idx);
    ushort8 v1 = *(const ushort8*)(P + pStr + idx);
    ushort8 v2 = *(const ushort8*)(P + 2 * pStr + idx);
    ushort8 v3 = *(const ushort8*)(P + 3 * pStr + idx);
#pragma unroll
    for (int j = 0; j < 8; ++j)
      a[sw * 8 + j] = bf2f(rv[j]) + bf2f(v0[j]) + bf2f(v1[j]) + bf2f(v2[j]) + bf2f(v3[j]);
  }
  float s = 0.f, ss = 0.f;
#pragma unroll
  for (int j = 0; j < 16; ++j) { s += a[j]; ss += a[j] * a[j]; }
#pragma unroll
  for (int off = 32; off > 0; off >>= 1) {
    s += __shfl_down(s, off);
    ss += __shfl_down(ss, off);
  }
  s = __shfl(s, 0);
  ss = __shfl(ss, 0);
  const float mean = s * (1.0f / 1024.0f);
  const float rstd = rsqrtf(ss * (1.0f / 1024.0f) - mean * mean + 1e-5f);
#pragma unroll
  for (int sw = 0; sw < 2; ++sw) {
    const int cbase = sw * 512 + lane * 8;
    float4 g0 = *(const float4*)(gg + cbase);
    float4 g1 = *(const float4*)(gg + cbase + 4);
    float4 b0 = *(const float4*)(bb + cbase);
    float4 b1 = *(const float4*)(bb + cbase + 4);
    const float* gp0 = &g0.x; const float* gp1 = &g1.x;
    const float* bp0 = &b0.x; const float* bp1 = &b1.x;
    float4 o0, o1;
    float* op0 = &o0.x; float* op1 = &o1.x;
#pragma unroll
    for (int j = 0; j < 4; ++j) {
      op0[j] = (a[sw * 8 + j]     - mean) * rstd * gp0[j] + bp0[j];
      op1[j] = (a[sw * 8 + 4 + j] - mean) * rstd * gp1[j] + bp1[j];
    }
    *(float4*)(out + rbase + cbase) = o0;
    *(float4*)(out + rbase + cbase + 4) = o1;
  }
}

// ---------------------------------------------------------------------------
// Attention is algebraically dead: softmax over q sums to 1 per (b,h,k) column;
// summed over k -> s_bh == S == 2048 exactly. Folding the residual too:
//   h1  = LN( z @ (I + 2048*Wv@Wo) + (2048*bv@Wo + bo) )
//   out = LN( h1 + relu(h1@W1+b1)@W2 + b2 )
// q, k, mask, x, y, Wq, Wk are all unused.
// ---------------------------------------------------------------------------
extern "C" void kernel_launch(void* const* d_in, const int* in_sizes, int n_in,
                              void* d_out, int out_size, void* d_ws, size_t ws_size,
                              hipStream_t stream) {
  const float* z  = (const float*)d_in[2];
  const float* Wv = (const float*)d_in[8];
  const float* bv = (const float*)d_in[9];
  const float* Wo = (const float*)d_in[10];
  const float* bo = (const float*)d_in[11];
  const float* W1 = (const float*)d_in[12];
  const float* b1 = (const float*)d_in[13];
  const float* W2 = (const float*)d_in[14];
  const float* b2 = (const float*)d_in[15];
  const float* lng = (const float*)d_in[16];
  const float* lnb = (const float*)d_in[17];
  float* out = (float*)d_out;

  char* ws = (char*)d_ws;
  // layout (MB offsets), peak 112MB, lifetimes checked:
  //   0..32  : a1 (FF1 out, alive to FF2)
  //   32..64 : attP bf16 4x8MB (dead after LN1) -> ffP bf16 4x8MB (alive to LN2)
  //   64..72 : W2T (prep out, read at FF2)
  //   72..80 : wcpB bf16 4x2MB (Wc partials, dead after combine)
  //   88..96 : WoT(88..90) WvBf(90..92) WcT(92..94) bc(94) bprt(94+64K)
  //   96..104: h1bf (LN1 out, alive to LN2)
  //   104..112: W1T (prep out, read at FF1)
  unsigned short* a1   = (unsigned short*)(ws + 0 * MB);
  unsigned short* attP = (unsigned short*)(ws + 32 * MB);
  unsigned short* ffP  = (unsigned short*)(ws + 32 * MB);
  unsigned short* W2T  = (unsigned short*)(ws + 64 * MB);
  unsigned short* wcpB = (unsigned short*)(ws + 72 * MB);
  unsigned short* WoT  = (unsigned short*)(ws + 88 * MB);
  unsigned short* WvBf = (unsigned short*)(ws + 90 * MB);
  unsigned short* WcT  = (unsigned short*)(ws + 92 * MB);
  float*          bc   = (float*)(ws + 94 * MB);
  float*          bprt = (float*)(ws + 94 * MB + 65536);
  unsigned short* h1bf = (unsigned short*)(ws + 96 * MB);
  unsigned short* W1T  = (unsigned short*)(ws + 104 * MB);

  const size_t pStr = (size_t)kM * kD;     // elements per activation partial
  const size_t wStr = (size_t)kD * kD;     // elements per Wc partial

  // 1) merged weight prep (WoT, W1T, W2T, WvBf, bprt)
  prep_kernel<<<dim3(3456), dim3(256), 0, stream>>>(
      Wo, Wv, W1, W2, bv, WoT, WvBf, W1T, W2T, bprt);

  // 2) Wc partials = (2048*Wv@Wo)^T : split-K x4 (grid 256, K=4 steps)
  gemm_bt<1, 0, 0><<<dim3(256), dim3(256), 0, stream>>>(
      WoT, WvBf, nullptr, wcpB, kD, kD, kD, kD / 128, 64, 256, wStr, 8, 4);

  // 3) WcT = sum of partials + I (bf16); blocks 0-3 also finish bc
  combine_wc4_fin_kernel<<<dim3(1024), dim3(256), 0, stream>>>(
      wcpB, WcT, bprt, bo, bc);

  // 4) attP = z @ WcT^T + bc : split-K x4 (grid 1024), A staged fp32->bf16
  gemm_bt<1, 0, 1><<<dim3(1024), dim3(256), 0, stream>>>(
      z, WcT, bc, attP, kM, kD, kD, kD / 128, 256, 256, pStr, 8, 8);

  // 5) h1 = LN(attP0..3) -> bf16 (wave-per-row)
  ln4_wave_kernel<<<dim3(kM / 4), dim3(256), 0, stream>>>(
      attP, pStr, lng, lnb, h1bf);

  // 6) FF1: a1 = relu(h1 @ W1 + b1) : grid 1024, chunk 16x8/XCD
  gemm_bt<1, 1, 0><<<dim3(1024), dim3(256), 0, stream>>>(
      h1bf, W1T, b1, a1, kM, kFF, kD, kFF / 128, 1024, kD, 0, 16, 8);

  // 7) FF2: ffP = a1 @ W2 + b2 : split-K x4 (grid 1024), chunk 16x8/XCD
  gemm_bt<1, 0, 0><<<dim3(1024), dim3(256), 0, stream>>>(
      a1, W2T, b2, ffP, kM, kD, kFF, kD / 128, 256, kFF / 4, pStr, 16, 8);

  // 8) out = LN(h1 + ffP0..3) (wave-per-row)
  ln_fin_wave_kernel<<<dim3(kM / 4), dim3(256), 0, stream>>>(
      h1bf, ffP, pStr, lng, lnb, out);
}